// Round 7
// baseline (1523.244 us; speedup 1.0000x reference)
//
#include <hip/hip_runtime.h>
#include <math.h>

#define NPTS 8192
#define KNNK 10

typedef __attribute__((ext_vector_type(8))) short bf16x8s;
typedef __attribute__((ext_vector_type(4))) float f32x4;

__device__ __forceinline__ float preluf(float v, float a){ return v >= 0.f ? v : a*v; }
__device__ __forceinline__ float4 f4fma(float a, float4 b, float4 c){
  return make_float4(fmaf(a,b.x,c.x), fmaf(a,b.y,c.y), fmaf(a,b.z,c.z), fmaf(a,b.w,c.w));
}

__device__ __forceinline__ void gl_lds16(const void* g, void* l){
  __builtin_amdgcn_global_load_lds((const __attribute__((address_space(1))) void*)g,
                                   (__attribute__((address_space(3))) void*)l, 16, 0, 0);
}
__device__ __forceinline__ void gl_lds4(const void* g, void* l){
  __builtin_amdgcn_global_load_lds((const __attribute__((address_space(1))) void*)g,
                                   (__attribute__((address_space(3))) void*)l, 4, 0, 0);
}

// f64 lex key: double(d) with j OR'd into the 29 zero low-mantissa bits.
// Gate g9 = min over the partner lists' d9 at last exchange: a dropped candidate
// has >=10 strictly-smaller-key entries already held for this query.
__device__ __forceinline__ void kinsd2(double* bk, float& g9, float pbd9, float d, int j){
  if (__any(d < g9)) {
    double t = (double)d;
    t = __longlong_as_double(__double_as_longlong(t) | (unsigned long long)(unsigned)j);
    #pragma unroll
    for (int s=0;s<10;++s){
      double mn = fmin(bk[s], t);
      double mx = fmax(bk[s], t);
      bk[s] = mn; t = mx;
    }
    g9 = fminf((float)bk[9], pbd9);   // (float)bk[9] rounds back to exact d9
  }
}

// split float into bf16 hi/lo (rne); returns packed hi pair, sets lo pair
__device__ __forceinline__ unsigned bfsplit2(float a, float b, unsigned& lo2){
  unsigned ua = __float_as_uint(a), ub = __float_as_uint(b);
  unsigned ha = (ua + 0x7FFFu + ((ua>>16)&1u)) & 0xFFFF0000u;
  unsigned hb = (ub + 0x7FFFu + ((ub>>16)&1u)) & 0xFFFF0000u;
  float ra = a - __uint_as_float(ha);
  float rb = b - __uint_as_float(hb);
  unsigned la = __float_as_uint(ra), lb = __float_as_uint(rb);
  unsigned qa = (la + 0x7FFFu + ((la>>16)&1u)) >> 16;
  unsigned qb = (lb + 0x7FFFu + ((lb>>16)&1u)) & 0xFFFF0000u;
  lo2 = qa | qb;
  return (ha >> 16) | hb;
}

// ---------- prep: x0pad (targets padded to 4ch) + sqnorm ----------
__global__ __launch_bounds__(256) void prep0_kernel(const float* __restrict__ T,
                                                    float* __restrict__ x0,
                                                    float* __restrict__ sqn){
  int p = blockIdx.x*256 + threadIdx.x;
  float t0 = T[p*3+0], t1 = T[p*3+1], t2 = T[p*3+2];
  *(float4*)(x0 + (size_t)p*4) = make_float4(t0,t1,t2,0.f);
  float s = fmaf(t0,t0,0.f); s = fmaf(t1,t1,s); s = fmaf(t2,t2,s); s = fmaf(0.f,0.f,s);
  sqn[p] = s;
}

// ---------- KNN C=64 (R7): TRANSPOSED GEMM -> lane-local scan.
// acc = mfma(A=xj, B=xq): C rows=j, cols=query. Lane lm owns query lm; its acc
// f32x4 holds 4 j-candidates -> scan in registers, no dch LDS, no barrier C.
// 4 kg-lanes per query each keep a top-10; shfl-butterfly threshold; 4-list merge.
// Block = 64 queries; 2-way j-split; grid 128x4x2 = 1024 = 4 blocks/CU x 256 CU.
__global__ __launch_bounds__(256, 4) void knn64_kernel(const unsigned short* __restrict__ Xh,
                                                       const unsigned short* __restrict__ Xl,
                                                       const float* __restrict__ sqn,
                                                       double* __restrict__ pk){
  __shared__ __align__(16) unsigned char smem[33792];
  // [0,16384)      xj_hi [128 j][64ch] ushort, XOR-swizzled rows
  // [16384,32768)  xj_lo
  // [32768,33792)  sx2j [2][128] f32 (double-buffered)
  // merge overlay: lst [64 q][4][10] f64 = 20480 B at offset 0
  float* sx2j = (float*)(smem + 32768);
  double* lst = (double*)smem;

  const int b   = blockIdx.y;
  const int q0  = blockIdx.x * 64;
  const int jh  = blockIdx.z;          // 0..1 j-half
  const int tid = threadIdx.x;
  const int L   = tid & 63;
  const int w   = tid >> 6;            // wave owns 16 queries
  const int lm  = L & 15;
  const int kg  = L >> 4;              // 4 scan lanes per query

  const size_t bbase = (size_t)b * NPTS;
  const int qi = q0 + w*16 + lm;       // this lane's query

  // xq fragments for this lane's query (B-operand layout == A's: lane row=lm, k-off kg*8)
  bf16x8s qh[2], ql[2];
  {
    const char* Qh = (const char*)Xh + (bbase + qi)*128;
    const char* Ql = (const char*)Xl + (bbase + qi)*128;
    #pragma unroll
    for (int kc=0;kc<2;++kc){
      qh[kc] = *(const bf16x8s*)(Qh + kc*64 + kg*16);
      ql[kc] = *(const bf16x8s*)(Ql + kc*64 + kg*16);
    }
  }
  const float x2q = sqn[bbase + qi];

  // staging source (inverse-swizzled so linear LDS dest ends up XOR-swizzled)
  const int srow = L >> 3;
  const unsigned soff = (unsigned)(((L & 7) ^ srow) << 4);
  const char* srch = (const char*)Xh + (bbase + (size_t)jh*4096 + w*32 + srow)*128 + soff;
  const char* srcl = (const char*)Xl + (bbase + (size_t)jh*4096 + w*32 + srow)*128 + soff;
  const float* sx2jsrc = sqn + bbase + jh*4096 + w*64 + L;

  // prologue: stage tile 0
  #pragma unroll
  for (int i=0;i<4;++i){
    gl_lds16(srch + i*1024, smem + w*4096 + i*1024);
    gl_lds16(srcl + i*1024, smem + 16384 + w*4096 + i*1024);
  }
  if (w < 2) gl_lds4(sx2jsrc, (char*)sx2j + w*256);

  double bk[10];
  float g9 = INFINITY, pbd9 = INFINITY;
  #pragma unroll
  for (int u=0;u<10;++u) bk[u] = (double)INFINITY;

  const char* xjh_c = (const char*)smem;
  const char* xjl_c = (const char*)smem + 16384;
  const unsigned swz = (unsigned)((lm & 7) << 4);

  for (int t = 0; t < 32; ++t) {
    __syncthreads();   // A: stage(t) landed (implicit vmcnt(0) before barrier)

    f32x4 acc[8];
    #pragma unroll
    for (int jb=0;jb<8;++jb) acc[jb] = (f32x4){0.f,0.f,0.f,0.f};

    #pragma unroll
    for (int kc=0;kc<2;++kc){
      const unsigned koff = (unsigned)(kc*64 + kg*16) ^ swz;
      #pragma unroll
      for (int jb=0;jb<8;++jb){
        const int rb = (jb*16 + lm)*128;
        bf16x8s jhf = *(const bf16x8s*)(xjh_c + rb + koff);
        bf16x8s jlf = *(const bf16x8s*)(xjl_c + rb + koff);
        // same product sequence as before: (qh*jh), (qh*jl), (ql*jh); A=j rows, B=q cols
        acc[jb] = __builtin_amdgcn_mfma_f32_16x16x32_bf16(jhf, qh[kc], acc[jb], 0,0,0);
        acc[jb] = __builtin_amdgcn_mfma_f32_16x16x32_bf16(jlf, qh[kc], acc[jb], 0,0,0);
        acc[jb] = __builtin_amdgcn_mfma_f32_16x16x32_bf16(jhf, ql[kc], acc[jb], 0,0,0);
      }
    }
    __syncthreads();   // B: all waves done reading xj(t) -> safe to overwrite

    if (t < 31){
      const char* nh = srch + (size_t)(t+1)*16384;
      const char* nl = srcl + (size_t)(t+1)*16384;
      #pragma unroll
      for (int i=0;i<4;++i){
        gl_lds16(nh + i*1024, smem + w*4096 + i*1024);
        gl_lds16(nl + i*1024, smem + 16384 + w*4096 + i*1024);
      }
      if (w < 2) gl_lds4(sx2jsrc + (size_t)(t+1)*128, (char*)sx2j + ((t+1)&1)*512 + w*256);
    }

    const int j0 = jh*4096 + t*128;
    const float* x2jb = sx2j + (t&1)*128;

    // lane-local scan: C rows = j = jb*16 + kg*4 + r, col = query = lm
    #pragma unroll
    for (int jb=0;jb<8;++jb){
      float4 xj2 = *(const float4*)&x2jb[jb*16 + kg*4];
      f32x4 c = acc[jb];
      float4 dv = make_float4(x2q + xj2.x - 2.0f*c[0],
                              x2q + xj2.y - 2.0f*c[1],
                              x2q + xj2.z - 2.0f*c[2],
                              x2q + xj2.w - 2.0f*c[3]);
      float m4 = fminf(fminf(dv.x,dv.y), fminf(dv.z,dv.w));
      if (__any(m4 < g9)){
        const int jj = j0 + jb*16 + kg*4;
        kinsd2(bk, g9, pbd9, dv.x, jj);
        kinsd2(bk, g9, pbd9, dv.y, jj+1);
        kinsd2(bk, g9, pbd9, dv.z, jj+2);
        kinsd2(bk, g9, pbd9, dv.w, jj+3);
      }
      if (jb & 1){
        // threshold butterfly across the 4 kg-lanes of this query
        float d9 = (float)bk[9];
        float m  = fminf(d9, __shfl_xor(d9, 16));
        float mm = fminf(m,  __shfl_xor(m, 32));
        pbd9 = mm;              // min over all 4 lists' d9 (own-new dominates own-old)
        g9 = mm;
      }
    }
  }

  // in-block merge of the 4 per-lane lists per query
  __syncthreads();
  #pragma unroll
  for (int u=0;u<10;++u) lst[(size_t)(w*16 + lm)*40 + kg*10 + u] = bk[u];
  __syncthreads();
  if (tid < 64) {
    const double* row = &lst[(size_t)tid*40];
    int i0=0, i1=0, i2=0, i3=0;
    size_t base = ((size_t)jh*(4*NPTS) + bbase + q0 + tid)*10;
    #pragma unroll
    for (int u=0;u<10;++u){
      double ka = row[i0], kb2 = row[10+i1], kc2 = row[20+i2], kd2 = row[30+i3];
      bool tab = ka  < kb2; double mab = tab ? ka  : kb2;
      bool tcd = kc2 < kd2; double mcd = tcd ? kc2 : kd2;
      bool tt  = mab < mcd; double m   = tt  ? mab : mcd;
      pk[base+u] = m;
      i0 += (tt && tab)  ? 1 : 0;
      i1 += (tt && !tab) ? 1 : 0;
      i2 += (!tt && tcd) ? 1 : 0;
      i3 += (!tt && !tcd)? 1 : 0;
    }
  }
}

// ---------- KNN for conv1 (C=4, fp32 VALU GEMM, exact self-dist) ----------
__global__ __launch_bounds__(256, 2) void knn4_kernel(const float* __restrict__ X,
                                                      const float* __restrict__ sqn,
                                                      double* __restrict__ pk){
  __shared__ __align__(16) float xqT[4*132];
  __shared__ __align__(16) float uni[10752];   // xjT[4][132] | dch[128][68] | lists f64
  __shared__ float s_x2q[128];
  __shared__ float s_x2j[128];
  __shared__ float sbd[2][128];

  const int b   = blockIdx.y;
  const int q0  = blockIdx.x * 128;
  const int jh  = blockIdx.z;
  const int tid = threadIdx.x;
  const int tn  = tid & 15;
  const int tm  = tid >> 4;
  const int tq  = tid & 127;
  const int th  = tid >> 7;

  const float* Xb = X + (size_t)b * NPTS * 4;

  for (int i = tid; i < 128; i += 256) {
    float4 v = *(const float4*)(Xb + (size_t)(q0+i)*4);
    xqT[0*132+i] = v.x; xqT[1*132+i] = v.y; xqT[2*132+i] = v.z; xqT[3*132+i] = v.w;
  }
  if (tid < 128) s_x2q[tid] = sqn[b*NPTS + q0 + tid];

  const int sw  = ((tn>>2)&3) << 2;
  const int bp0 = (tn*8)     ^ sw;
  const int bp1 = (tn*8 + 4) ^ sw;

  double bk[10];
  float g9 = INFINITY, pbd9 = INFINITY;
  #pragma unroll
  for (int u=0;u<10;++u) bk[u] = (double)INFINITY;

  for (int t = 0; t < 32; ++t) {
    const int j0 = jh*4096 + t*128;
    for (int i = tid; i < 128; i += 256) {
      float4 v = *(const float4*)(Xb + (size_t)(j0+i)*4);
      int pj = i ^ (((i>>5)&3) << 2);
      uni[0*132+pj] = v.x; uni[1*132+pj] = v.y; uni[2*132+pj] = v.z; uni[3*132+pj] = v.w;
    }
    if (tid < 128) s_x2j[tid] = sqn[b*NPTS + j0 + tid];
    __syncthreads();   // A

    float acc[8][8];
    #pragma unroll
    for (int i=0;i<8;++i)
      #pragma unroll
      for (int j=0;j<8;++j) acc[i][j] = 0.f;

    #pragma unroll
    for (int kk=0; kk<4; ++kk) {
      float av[8], bv[8];
      *(float4*)&av[0] = *(const float4*)&xqT[kk*132 + tm*8];
      *(float4*)&av[4] = *(const float4*)&xqT[kk*132 + tm*8 + 4];
      *(float4*)&bv[0] = *(const float4*)&uni[kk*132 + bp0];
      *(float4*)&bv[4] = *(const float4*)&uni[kk*132 + bp1];
      #pragma unroll
      for (int i=0;i<8;++i)
        #pragma unroll
        for (int j=0;j<8;++j)
          acc[i][j] = fmaf(av[i], bv[j], acc[i][j]);
    }
    __syncthreads();   // B: gemm reads done; uni becomes dch[128][68]

    #pragma unroll
    for (int h=0; h<2; ++h) {
      if ((tn>>3) == h) {
        #pragma unroll
        for (int qi=0; qi<8; ++qi) {
          const int row = tm*8 + qi;
          const float xq2 = s_x2q[row];
          float vv[8];
          #pragma unroll
          for (int u=0;u<8;++u)
            vv[u] = xq2 + s_x2j[tn*8 + u] - 2.f*acc[qi][u];
          *(float4*)&uni[row*68 + (tn&7)*8]     = make_float4(vv[0],vv[1],vv[2],vv[3]);
          *(float4*)&uni[row*68 + (tn&7)*8 + 4] = make_float4(vv[4],vv[5],vv[6],vv[7]);
        }
      }
      __syncthreads();   // C
      {
        const int jb0 = j0 + h*64 + th*32;
        #pragma unroll
        for (int c4=0;c4<8;++c4){
          float4 dv = *(const float4*)&uni[tq*68 + th*32 + c4*4];
          int jj = jb0 + c4*4;
          kinsd2(bk, g9, pbd9, dv.x, jj);
          kinsd2(bk, g9, pbd9, dv.y, jj+1);
          kinsd2(bk, g9, pbd9, dv.z, jj+2);
          kinsd2(bk, g9, pbd9, dv.w, jj+3);
        }
      }
      if (h == 1) sbd[th][tq] = (float)bk[9];
      __syncthreads();   // D
      if (h == 1){
        pbd9 = sbd[1^th][tq];
        g9 = fminf((float)bk[9], pbd9);
      }
    }
  }

  double* lst = (double*)uni;    // [128][20]
  #pragma unroll
  for (int u=0;u<10;++u) lst[tq*20 + th*10 + u] = bk[u];
  __syncthreads();
  if (tid < 128) {
    const double* row = &lst[tid*20];
    int ia=0, ib=0;
    size_t base = ((size_t)jh*(4*NPTS) + (size_t)b*NPTS + q0 + tid)*10;
    #pragma unroll
    for (int u=0;u<10;++u){
      double ka = row[ia], kb2 = row[10+ib];
      bool ta = ka < kb2;
      pk[base+u] = ta ? ka : kb2;
      ia += ta ? 1 : 0; ib += ta ? 0 : 1;
    }
  }
}

// ---------- merge the 2 j-half partial f64-key lists -> final idx ----------
__global__ __launch_bounds__(256) void knnmerge_kernel(const double* __restrict__ pk,
                                                       int* __restrict__ idxout){
  int p = blockIdx.x*256 + threadIdx.x;   // 0..32767
  const double* A = pk + (size_t)p*10;
  const double* B = pk + (size_t)(4*NPTS)*10 + (size_t)p*10;
  int ia=0, ib=0;
  int* op = idxout + (size_t)p*10;
  #pragma unroll
  for (int u=0;u<10;++u){
    double ka = A[ia], kb = B[ib];
    bool t = ka < kb;
    op[u] = (int)(__double_as_longlong(t ? ka : kb) & 8191LL);
    ia += t ? 1 : 0; ib += t ? 0 : 1;
  }
}

// ---------- prep U/D for 64-ch edge conv (wave-per-point, lane-per-output) ----------
__global__ __launch_bounds__(256) void prepUD64_kernel(const float* __restrict__ XC, int cin,
                                                       const float* __restrict__ W,
                                                       float* __restrict__ U,
                                                       float* __restrict__ D){
  const int tid = threadIdx.x;
  const int w = tid >> 6, o = tid & 63;
  const int p = blockIdx.x*4 + w;
  const float* xr = XC + (size_t)p*192 + cin;   // wave-uniform base
  float zu = 0.f, zd = 0.f;
  #pragma unroll
  for (int c=0;c<64;++c){
    float xc = xr[c];                  // uniform across the wave
    float wt = W[c*64 + o];
    float wb = W[(64+c)*64 + o];
    zu = fmaf(xc, wt, zu);
    zd = fmaf(xc, wb - wt, zd);
  }
  U[(size_t)p*64 + o] = zu;
  D[(size_t)p*64 + o] = zd;
}

// ---------- prep U/D for conv1 ----------
__global__ __launch_bounds__(256) void prepUD12_kernel(const float* __restrict__ T,
                                                       const float* __restrict__ W1,
                                                       float* __restrict__ U,
                                                       float* __restrict__ D){
  int p = blockIdx.x*256 + threadIdx.x;
  float t[3] = {T[p*3+0], T[p*3+1], T[p*3+2]};
  const float4* W = (const float4*)W1;
  float4 u[16], q[16];
  #pragma unroll
  for (int o=0;o<16;++o){ u[o]=make_float4(0,0,0,0); q[o]=make_float4(0,0,0,0); }
  #pragma unroll
  for (int c=0;c<3;++c){
    const float tc = t[c];
    #pragma unroll
    for (int o=0;o<16;++o){
      float4 ws  = W[c*16+o],     ws2 = W[(c+3)*16+o];
      float4 wq  = W[(c+6)*16+o], wq2 = W[(c+9)*16+o];
      u[o] = f4fma(tc, make_float4(ws.x+ws2.x, ws.y+ws2.y, ws.z+ws2.z, ws.w+ws2.w), u[o]);
      q[o] = f4fma(tc, make_float4(wq.x+wq2.x, wq.y+wq2.y, wq.z+wq2.z, wq.w+wq2.w), q[o]);
    }
  }
  float4* up = (float4*)(U + (size_t)p*64);
  float4* dp = (float4*)(D + (size_t)p*64);
  #pragma unroll
  for (int o=0;o<16;++o){
    up[o] = u[o];
    dp[o] = make_float4(q[o].x-u[o].x, q[o].y-u[o].y, q[o].z-u[o].z, q[o].w-u[o].w);
  }
}

// ---------- two-layer edge conv + fused sqnorm + fused bf16 hi/lo split ----------
__global__ __launch_bounds__(256) void edge2w_kernel(const float* __restrict__ U,
                                                     const float* __restrict__ Dp,
                                                     const int* __restrict__ idx,
                                                     const float* __restrict__ Wb,
                                                     const float* __restrict__ PA, int paa, int pab,
                                                     float* __restrict__ out, int coff,
                                                     float* __restrict__ sqnout,
                                                     unsigned short* __restrict__ Xh,
                                                     unsigned short* __restrict__ Xl){
  __shared__ __align__(16) float sh[4][10][68];
  const int tid = threadIdx.x;
  const int w = tid >> 6, o = tid & 63;
  const int p = blockIdx.x*4 + w, b = p >> 13;
  const float aa = PA[paa], ab = PA[pab];

  float wreg[64];
  #pragma unroll
  for (int c=0;c<64;++c) wreg[c] = Wb[c*64 + o];

  const float dc = Dp[(size_t)p*64 + o];

  #pragma unroll
  for (int k=0;k<10;++k){
    int nb = idx[p*10 + k];
    float u = U[((size_t)(b<<13)+nb)*64 + o];
    sh[w][k][o] = preluf(u + dc, aa);
  }
  __syncthreads();

  float mx = -INFINITY;
  #pragma unroll 2
  for (int k=0;k<10;++k){
    float a0=0.f,a1=0.f,a2=0.f,a3=0.f;
    #pragma unroll
    for (int c4=0;c4<16;++c4){
      float4 hv = *(const float4*)&sh[w][k][c4*4];
      a0 = fmaf(hv.x, wreg[c4*4+0], a0);
      a1 = fmaf(hv.y, wreg[c4*4+1], a1);
      a2 = fmaf(hv.z, wreg[c4*4+2], a2);
      a3 = fmaf(hv.w, wreg[c4*4+3], a3);
    }
    float z = (a0+a1)+(a2+a3);
    mx = fmaxf(mx, preluf(z, ab));
  }
  out[(size_t)p*192 + coff + o] = mx;
  // fused bf16 hi/lo split of the output (feeds next conv's KNN GEMM)
  {
    unsigned um = __float_as_uint(mx);
    unsigned h  = (um + 0x7FFFu + ((um>>16)&1u)) & 0xFFFF0000u;
    float rr = mx - __uint_as_float(h);
    unsigned ur = __float_as_uint(rr);
    unsigned l  = (ur + 0x7FFFu + ((ur>>16)&1u)) >> 16;
    Xh[(size_t)p*64 + o] = (unsigned short)(h >> 16);
    Xl[(size_t)p*64 + o] = (unsigned short)l;
  }
  // fused sqnorm of this 64-col output row
  float sq = mx*mx;
  #pragma unroll
  for (int off=1; off<64; off<<=1) sq += __shfl_xor(sq, off);
  if (o == 0) sqnout[p] = sq;
}

// ---------- single-layer edge conv (conv3), wave-per-point ----------
__global__ __launch_bounds__(256) void edge1w_kernel(const float* __restrict__ U,
                                                     const float* __restrict__ Dp,
                                                     const int* __restrict__ idx,
                                                     const float* __restrict__ PA, int paa,
                                                     float* __restrict__ out, int coff){
  const int tid = threadIdx.x;
  const int w = tid >> 6, o = tid & 63;
  const int p = blockIdx.x*4 + w, b = p >> 13;
  const float aa = PA[paa];
  const float dc = Dp[(size_t)p*64 + o];
  float mx = -INFINITY;
  #pragma unroll
  for (int k=0;k<10;++k){
    int nb = idx[p*10 + k];
    float u = U[((size_t)(b<<13)+nb)*64 + o];
    mx = fmaxf(mx, preluf(u + dc, aa));
  }
  out[(size_t)p*192 + coff + o] = mx;
}

// ---------- fused weight prep: all four head weights -> hi/lo transposed ----------
__global__ __launch_bounds__(256) void prepWall_kernel(const float* __restrict__ W6,
                                                       const float* __restrict__ W7,
                                                       const float* __restrict__ W8,
                                                       const float* __restrict__ W9,
                                                       unsigned short* __restrict__ Wh6, unsigned short* __restrict__ Wl6,
                                                       unsigned short* __restrict__ Wh7, unsigned short* __restrict__ Wl7,
                                                       unsigned short* __restrict__ Wh8, unsigned short* __restrict__ Wl8,
                                                       unsigned short* __restrict__ Wh9, unsigned short* __restrict__ Wl9){
  int bb = blockIdx.x;
  const float* W; unsigned short *Wh, *Wl; int K, N, k;
  if (bb < 192)      { W=W6; Wh=Wh6; Wl=Wl6; K=192; N=1024; k=bb; }
  else if (bb < 384) { W=W7; Wh=Wh7; Wl=Wl7; K=192; N=256;  k=bb-192; }
  else if (bb < 640) { W=W8; Wh=Wh8; Wl=Wl8; K=256; N=256;  k=bb-384; }
  else               { W=W9; Wh=Wh9; Wl=Wl9; K=256; N=128;  k=bb-640; }
  for (int n = threadIdx.x; n < N; n += 256){
    float v = W[(size_t)k*N + n];
    unsigned ua = __float_as_uint(v);
    unsigned h = (ua + 0x7FFFu + ((ua>>16)&1u)) & 0xFFFF0000u;
    float r = v - __uint_as_float(h);
    unsigned ub = __float_as_uint(r);
    unsigned l = (ub + 0x7FFFu + ((ub>>16)&1u)) >> 16;
    Wh[(size_t)n*K + k] = (unsigned short)(h >> 16);
    Wl[(size_t)n*K + k] = (unsigned short)l;
  }
}

// ---------- MFMA bf16 hi/lo GEMM: C = prelu(A@W [+bias]); EPI2: colmax partials ----------
template<int EPI>
__global__ __launch_bounds__(256, 2) void mgemm_kernel(const float* __restrict__ A, int lda,
                                                       const unsigned short* __restrict__ WhT,
                                                       const unsigned short* __restrict__ WlT,
                                                       int K,
                                                       float* __restrict__ C, int ldc,
                                                       const float* __restrict__ bias,
                                                       const float* __restrict__ PA, int pidx,
                                                       int Ntot){
  __shared__ __align__(16) unsigned char smem[73728];
  unsigned short* sa = (unsigned short*)smem;
  unsigned short* sb = (unsigned short*)(smem + 36864);
  float* cst = (float*)smem;

  const int tid = threadIdx.x;
  const int m0 = blockIdx.x*128, n0 = blockIdx.y*128;
  const int L = tid & 63, w = tid >> 6;
  const int lm = L & 15, kg = L >> 4;

  f32x4 acc[2][8];
  #pragma unroll
  for (int mt=0;mt<2;++mt)
    #pragma unroll
    for (int nt=0;nt<8;++nt) acc[mt][nt] = (f32x4){0.f,0.f,0.f,0.f};

  for (int c0 = 0; c0 < K; c0 += 64) {
    __syncthreads();
    #pragma unroll
    for (int s=0;s<8;++s){
      int e = tid + s*256;
      int r = e >> 4, kq = (e & 15) << 2;
      float4 v = *(const float4*)(A + (size_t)(m0+r)*lda + c0 + kq);
      unsigned lo01, lo23;
      unsigned hi01 = bfsplit2(v.x, v.y, lo01);
      unsigned hi23 = bfsplit2(v.z, v.w, lo23);
      uint2 hp; hp.x = hi01; hp.y = hi23;
      uint2 lp; lp.x = lo01; lp.y = lo23;
      *(uint2*)&sa[r*72 + kq]        = hp;
      *(uint2*)&sa[9216 + r*72 + kq] = lp;
    }
    #pragma unroll
    for (int s=0;s<4;++s){
      int e = tid + s*256;
      int col = e >> 3, ko = (e & 7) << 3;
      *(uint4*)&sb[col*72 + ko]        = *(const uint4*)&WhT[(size_t)(n0+col)*K + c0 + ko];
      *(uint4*)&sb[9216 + col*72 + ko] = *(const uint4*)&WlT[(size_t)(n0+col)*K + c0 + ko];
    }
    __syncthreads();

    #pragma unroll
    for (int kc=0;kc<2;++kc){
      const int ko = kc*32 + kg*8;
      bf16x8s ah[2], al[2];
      #pragma unroll
      for (int mt=0;mt<2;++mt){
        int q = w*32 + mt*16 + lm;
        ah[mt] = *(const bf16x8s*)&sa[q*72 + ko];
        al[mt] = *(const bf16x8s*)&sa[9216 + q*72 + ko];
      }
      #pragma unroll
      for (int nt=0;nt<8;++nt){
        int n = nt*16 + lm;
        bf16x8s bh = *(const bf16x8s*)&sb[n*72 + ko];
        bf16x8s bl = *(const bf16x8s*)&sb[9216 + n*72 + ko];
        #pragma unroll
        for (int mt=0;mt<2;++mt){
          acc[mt][nt] = __builtin_amdgcn_mfma_f32_16x16x32_bf16(ah[mt], bh, acc[mt][nt], 0,0,0);
          acc[mt][nt] = __builtin_amdgcn_mfma_f32_16x16x32_bf16(ah[mt], bl, acc[mt][nt], 0,0,0);
          acc[mt][nt] = __builtin_amdgcn_mfma_f32_16x16x32_bf16(al[mt], bh, acc[mt][nt], 0,0,0);
        }
      }
    }
  }
  __syncthreads();

  const float a = PA[pidx];
  if (EPI == 2) {
    #pragma unroll
    for (int nt=0;nt<8;++nt){
      f32x4 c0v = acc[0][nt], c1v = acc[1][nt];
      float m = -INFINITY;
      #pragma unroll
      for (int r=0;r<4;++r){ m = fmaxf(m, preluf(c0v[r], a)); m = fmaxf(m, preluf(c1v[r], a)); }
      m = fmaxf(m, __shfl_xor(m, 16));
      m = fmaxf(m, __shfl_xor(m, 32));
      if (kg == 0) cst[w*128 + nt*16 + lm] = m;
    }
    __syncthreads();
    if (tid < 128){
      float m = fmaxf(fmaxf(cst[tid], cst[128+tid]), fmaxf(cst[256+tid], cst[384+tid]));
      C[(size_t)blockIdx.x*Ntot + n0 + tid] = m;
    }
  } else {
    float bc[8];
    if (EPI == 1){
      int bb = m0 >> 13;
      #pragma unroll
      for (int nt=0;nt<8;++nt) bc[nt] = bias[bb*256 + n0 + nt*16 + lm];
    }
    #pragma unroll
    for (int mt=0;mt<2;++mt){
      #pragma unroll
      for (int nt=0;nt<8;++nt){
        f32x4 c = acc[mt][nt];
        int col = nt*16 + lm;
        #pragma unroll
        for (int r=0;r<4;++r){
          int row = w*32 + mt*16 + kg*4 + r;
          float v = c[r] + (EPI==1 ? bc[nt] : 0.f);
          cst[row*132 + col] = preluf(v, a);
        }
      }
    }
    __syncthreads();
    const int tm = tid & 15, tn = tid >> 4;
    #pragma unroll
    for (int i=0;i<8;++i){
      int row = tm*8 + i;
      float4 v0 = *(const float4*)&cst[row*132 + tn*8];
      float4 v1 = *(const float4*)&cst[row*132 + tn*8 + 4];
      float* cp = C + (size_t)(m0 + row)*ldc + n0 + tn*8;
      *(float4*)cp     = v0;
      *(float4*)(cp+4) = v1;
    }
  }
}

__global__ __launch_bounds__(256) void reduce_pmax(const float* __restrict__ pmax,
                                                   float* __restrict__ x5m){
  int t = blockIdx.x*256 + threadIdx.x;
  if (t < 4096) {
    int b = t >> 10, o = t & 1023;
    float m = -INFINITY;
    for (int mt=0; mt<64; ++mt) m = fmaxf(m, pmax[((size_t)(b*64+mt))*1024 + o]);
    x5m[t] = m;
  }
}

__global__ __launch_bounds__(256) void bias7_kernel(const float* __restrict__ x5m,
                                                    const float* __restrict__ W7,
                                                    float* __restrict__ b7){
  int b = blockIdx.x; int o = threadIdx.x;
  float s = 0.f;
  for (int j=0;j<1024;++j) s = fmaf(x5m[b*1024+j], W7[(size_t)(192+j)*256 + o], s);
  b7[b*256+o] = s;
}

__global__ __launch_bounds__(256) void final10_kernel(const float* __restrict__ y3,
                                                      const float* __restrict__ W10,
                                                      const float* __restrict__ PA,
                                                      float* __restrict__ out){
  int p = blockIdx.x*256 + threadIdx.x;
  const float4* r = (const float4*)(y3 + (size_t)p*128);
  float s0=0.f, s1=0.f;
  #pragma unroll
  for (int c4=0;c4<32;++c4){
    float4 v = r[c4];
    s0 = fmaf(v.x, W10[(c4*4+0)*2+0], s0); s1 = fmaf(v.x, W10[(c4*4+0)*2+1], s1);
    s0 = fmaf(v.y, W10[(c4*4+1)*2+0], s0); s1 = fmaf(v.y, W10[(c4*4+1)*2+1], s1);
    s0 = fmaf(v.z, W10[(c4*4+2)*2+0], s0); s1 = fmaf(v.z, W10[(c4*4+2)*2+1], s1);
    s0 = fmaf(v.w, W10[(c4*4+3)*2+0], s0); s1 = fmaf(v.w, W10[(c4*4+3)*2+1], s1);
  }
  float a = PA[9];
  out[p*2+0] = s0>=0.f? s0 : a*s0;
  out[p*2+1] = s1>=0.f? s1 : a*s1;
}

extern "C" void kernel_launch(void* const* d_in, const int* in_sizes, int n_in,
                              void* d_out, int out_size, void* d_ws, size_t ws_size,
                              hipStream_t stream) {
  const float* T   = (const float*)d_in[0];
  const float* W1  = (const float*)d_in[1];
  const float* W2  = (const float*)d_in[2];
  const float* W3  = (const float*)d_in[3];
  const float* W4  = (const float*)d_in[4];
  const float* W5  = (const float*)d_in[5];
  const float* W6  = (const float*)d_in[6];
  const float* W7  = (const float*)d_in[7];
  const float* W8  = (const float*)d_in[8];
  const float* W9  = (const float*)d_in[9];
  const float* W10 = (const float*)d_in[10];
  const float* PA  = (const float*)d_in[11];

  float* ws   = (float*)d_ws;
  float* x0   = ws + 0;                // 131072
  float* sqn0 = ws + 131072;           // 32768
  float* sqn1 = ws + 163840;           // 32768
  float* sqn2 = ws + 196608;           // 32768
  int*   idx0 = (int*)(ws + 229376);   // 327680
  int*   idx1 = (int*)(ws + 557056);   // 327680
  int*   idx2 = (int*)(ws + 884736);   // 327680
  float* xcat = ws + 1212416;          // 6291456  [B,N,192]
  float* pmax = ws + 7503872;          // 262144
  float* x5m  = ws + 7766016;          // 4096
  float* b7   = ws + 7770112;          // 1024
  float* y1   = ws + 7771136;          // 8388608 floats (aliased: U / pk / Xh / Xl)
  float* y2   = ws + 16159744;         // 8388608  (aliased: D)
  float* y3   = xcat;
  float* U    = y1;                            // [32768][64] f32 = 2M floats
  float* D    = y2;
  double* pk  = (double*)y1;                   // [2][32768][10] f64 = 1.31M floats
  unsigned short* Xh = (unsigned short*)(y1 + 3145728);  // 4 MB, floats [3.0M,4.0M)
  unsigned short* Xl = (unsigned short*)(y1 + 4194304);  // 4 MB, floats [4.0M,5.0M)

  // split/transposed weights: reuse idx region (dead after edge1w)
  unsigned short* wsc = (unsigned short*)(ws + 229376);
  unsigned short* Wh6 = wsc;
  unsigned short* Wl6 = wsc + 196608;
  unsigned short* Wh7 = wsc + 393216;
  unsigned short* Wl7 = wsc + 442368;
  unsigned short* Wh8 = wsc + 491520;
  unsigned short* Wl8 = wsc + 557056;
  unsigned short* Wh9 = wsc + 622592;
  unsigned short* Wl9 = wsc + 655360;

  // conv1
  prep0_kernel<<<128, 256, 0, stream>>>(T, x0, sqn0);
  knn4_kernel<<<dim3(64,4,2), 256, 0, stream>>>(x0, sqn0, pk);
  knnmerge_kernel<<<128, 256, 0, stream>>>(pk, idx0);
  prepUD12_kernel<<<128, 256, 0, stream>>>(T, W1, U, D);
  edge2w_kernel<<<8192, 256, 0, stream>>>(U, D, idx0, W2, PA, 0, 1, xcat, 0, sqn1, Xh, Xl);

  // conv2
  knn64_kernel<<<dim3(128,4,2), 256, 0, stream>>>(Xh, Xl, sqn1, pk);
  knnmerge_kernel<<<128, 256, 0, stream>>>(pk, idx1);
  prepUD64_kernel<<<8192, 256, 0, stream>>>(xcat, 0, W3, U, D);
  edge2w_kernel<<<8192, 256, 0, stream>>>(U, D, idx1, W4, PA, 2, 3, xcat, 64, sqn2, Xh, Xl);

  // conv3
  knn64_kernel<<<dim3(128,4,2), 256, 0, stream>>>(Xh, Xl, sqn2, pk);
  knnmerge_kernel<<<128, 256, 0, stream>>>(pk, idx2);
  prepUD64_kernel<<<8192, 256, 0, stream>>>(xcat, 64, W5, U, D);
  edge1w_kernel<<<8192, 256, 0, stream>>>(U, D, idx2, PA, 4, xcat, 128);

  // head weights -> bf16 hi/lo transposed (one fused launch)
  prepWall_kernel<<<896, 256, 0, stream>>>(W6, W7, W8, W9,
                                           Wh6, Wl6, Wh7, Wl7, Wh8, Wl8, Wh9, Wl9);

  // head
  mgemm_kernel<2><<<dim3(256,8), 256, 0, stream>>>(xcat, 192, Wh6, Wl6, 192, pmax, 0, nullptr, PA, 5, 1024);
  reduce_pmax<<<16, 256, 0, stream>>>(pmax, x5m);
  bias7_kernel<<<4, 256, 0, stream>>>(x5m, W7, b7);
  mgemm_kernel<1><<<dim3(256,2), 256, 0, stream>>>(xcat, 192, Wh7, Wl7, 192, y1, 256, b7, PA, 6, 0);
  mgemm_kernel<0><<<dim3(256,2), 256, 0, stream>>>(y1, 256, Wh8, Wl8, 256, y2, 256, nullptr, PA, 7, 0);
  mgemm_kernel<0><<<dim3(256,1), 256, 0, stream>>>(y2, 256, Wh9, Wl9, 256, y3, 128, nullptr, PA, 8, 0);
  final10_kernel<<<128, 256, 0, stream>>>(y3, W10, PA, (float*)d_out);
}

// Round 8
// 1516.671 us; speedup vs baseline: 1.0043x; 1.0043x over previous
//
#include <hip/hip_runtime.h>
#include <math.h>

#define NPTS 8192
#define KNNK 10

typedef __attribute__((ext_vector_type(8))) short bf16x8s;
typedef __attribute__((ext_vector_type(4))) float f32x4;

__device__ __forceinline__ float preluf(float v, float a){ return v >= 0.f ? v : a*v; }
__device__ __forceinline__ float4 f4fma(float a, float4 b, float4 c){
  return make_float4(fmaf(a,b.x,c.x), fmaf(a,b.y,c.y), fmaf(a,b.z,c.z), fmaf(a,b.w,c.w));
}

__device__ __forceinline__ void gl_lds16(const void* g, void* l){
  __builtin_amdgcn_global_load_lds((const __attribute__((address_space(1))) void*)g,
                                   (__attribute__((address_space(3))) void*)l, 16, 0, 0);
}
__device__ __forceinline__ void gl_lds4(const void* g, void* l){
  __builtin_amdgcn_global_load_lds((const __attribute__((address_space(1))) void*)g,
                                   (__attribute__((address_space(3))) void*)l, 4, 0, 0);
}

// f64 lex key: double(d) with j OR'd into the 29 zero low-mantissa bits.
// Gate g9 = min over the partner lists' d9 at last exchange: a dropped candidate
// has >=10 strictly-smaller-key entries already held for this query.
__device__ __forceinline__ void kinsd2(double* bk, float& g9, float pbd9, float d, int j){
  if (__any(d < g9)) {
    double t = (double)d;
    t = __longlong_as_double(__double_as_longlong(t) | (unsigned long long)(unsigned)j);
    #pragma unroll
    for (int s=0;s<10;++s){
      double mn = fmin(bk[s], t);
      double mx = fmax(bk[s], t);
      bk[s] = mn; t = mx;
    }
    g9 = fminf((float)bk[9], pbd9);   // (float)bk[9] rounds back to exact d9
  }
}

// split float into bf16 hi/lo (rne); returns packed hi pair, sets lo pair
__device__ __forceinline__ unsigned bfsplit2(float a, float b, unsigned& lo2){
  unsigned ua = __float_as_uint(a), ub = __float_as_uint(b);
  unsigned ha = (ua + 0x7FFFu + ((ua>>16)&1u)) & 0xFFFF0000u;
  unsigned hb = (ub + 0x7FFFu + ((ub>>16)&1u)) & 0xFFFF0000u;
  float ra = a - __uint_as_float(ha);
  float rb = b - __uint_as_float(hb);
  unsigned la = __float_as_uint(ra), lb = __float_as_uint(rb);
  unsigned qa = (la + 0x7FFFu + ((la>>16)&1u)) >> 16;
  unsigned qb = (lb + 0x7FFFu + ((lb>>16)&1u)) & 0xFFFF0000u;
  lo2 = qa | qb;
  return (ha >> 16) | hb;
}

// ---------- prep: x0pad (targets padded to 4ch) + sqnorm ----------
__global__ __launch_bounds__(256) void prep0_kernel(const float* __restrict__ T,
                                                    float* __restrict__ x0,
                                                    float* __restrict__ sqn){
  int p = blockIdx.x*256 + threadIdx.x;
  float t0 = T[p*3+0], t1 = T[p*3+1], t2 = T[p*3+2];
  *(float4*)(x0 + (size_t)p*4) = make_float4(t0,t1,t2,0.f);
  float s = fmaf(t0,t0,0.f); s = fmaf(t1,t1,s); s = fmaf(t2,t2,s); s = fmaf(0.f,0.f,s);
  sqn[p] = s;
}

// ---------- KNN C=64 (R7): TRANSPOSED GEMM -> lane-local scan. ----------
__global__ __launch_bounds__(256, 4) void knn64_kernel(const unsigned short* __restrict__ Xh,
                                                       const unsigned short* __restrict__ Xl,
                                                       const float* __restrict__ sqn,
                                                       double* __restrict__ pk){
  __shared__ __align__(16) unsigned char smem[33792];
  // [0,16384) xj_hi [128 j][64ch] ushort XOR-swz ; [16384,32768) xj_lo ; [32768,33792) sx2j [2][128]
  // merge overlay: lst [64 q][4][10] f64 at offset 0
  float* sx2j = (float*)(smem + 32768);
  double* lst = (double*)smem;

  const int b   = blockIdx.y;
  const int q0  = blockIdx.x * 64;
  const int jh  = blockIdx.z;          // 0..1 j-half
  const int tid = threadIdx.x;
  const int L   = tid & 63;
  const int w   = tid >> 6;            // wave owns 16 queries
  const int lm  = L & 15;
  const int kg  = L >> 4;              // 4 scan lanes per query

  const size_t bbase = (size_t)b * NPTS;
  const int qi = q0 + w*16 + lm;       // this lane's query

  bf16x8s qh[2], ql[2];
  {
    const char* Qh = (const char*)Xh + (bbase + qi)*128;
    const char* Ql = (const char*)Xl + (bbase + qi)*128;
    #pragma unroll
    for (int kc=0;kc<2;++kc){
      qh[kc] = *(const bf16x8s*)(Qh + kc*64 + kg*16);
      ql[kc] = *(const bf16x8s*)(Ql + kc*64 + kg*16);
    }
  }
  const float x2q = sqn[bbase + qi];

  const int srow = L >> 3;
  const unsigned soff = (unsigned)(((L & 7) ^ srow) << 4);
  const char* srch = (const char*)Xh + (bbase + (size_t)jh*4096 + w*32 + srow)*128 + soff;
  const char* srcl = (const char*)Xl + (bbase + (size_t)jh*4096 + w*32 + srow)*128 + soff;
  const float* sx2jsrc = sqn + bbase + jh*4096 + w*64 + L;

  #pragma unroll
  for (int i=0;i<4;++i){
    gl_lds16(srch + i*1024, smem + w*4096 + i*1024);
    gl_lds16(srcl + i*1024, smem + 16384 + w*4096 + i*1024);
  }
  if (w < 2) gl_lds4(sx2jsrc, (char*)sx2j + w*256);

  double bk[10];
  float g9 = INFINITY, pbd9 = INFINITY;
  #pragma unroll
  for (int u=0;u<10;++u) bk[u] = (double)INFINITY;

  const char* xjh_c = (const char*)smem;
  const char* xjl_c = (const char*)smem + 16384;
  const unsigned swz = (unsigned)((lm & 7) << 4);

  for (int t = 0; t < 32; ++t) {
    __syncthreads();   // A: stage(t) landed (implicit vmcnt(0) before barrier)

    f32x4 acc[8];
    #pragma unroll
    for (int jb=0;jb<8;++jb) acc[jb] = (f32x4){0.f,0.f,0.f,0.f};

    #pragma unroll
    for (int kc=0;kc<2;++kc){
      const unsigned koff = (unsigned)(kc*64 + kg*16) ^ swz;
      #pragma unroll
      for (int jb=0;jb<8;++jb){
        const int rb = (jb*16 + lm)*128;
        bf16x8s jhf = *(const bf16x8s*)(xjh_c + rb + koff);
        bf16x8s jlf = *(const bf16x8s*)(xjl_c + rb + koff);
        acc[jb] = __builtin_amdgcn_mfma_f32_16x16x32_bf16(jhf, qh[kc], acc[jb], 0,0,0);
        acc[jb] = __builtin_amdgcn_mfma_f32_16x16x32_bf16(jlf, qh[kc], acc[jb], 0,0,0);
        acc[jb] = __builtin_amdgcn_mfma_f32_16x16x32_bf16(jhf, ql[kc], acc[jb], 0,0,0);
      }
    }
    __syncthreads();   // B: all waves done reading xj(t) -> safe to overwrite

    if (t < 31){
      const char* nh = srch + (size_t)(t+1)*16384;
      const char* nl = srcl + (size_t)(t+1)*16384;
      #pragma unroll
      for (int i=0;i<4;++i){
        gl_lds16(nh + i*1024, smem + w*4096 + i*1024);
        gl_lds16(nl + i*1024, smem + 16384 + w*4096 + i*1024);
      }
      if (w < 2) gl_lds4(sx2jsrc + (size_t)(t+1)*128, (char*)sx2j + ((t+1)&1)*512 + w*256);
    }

    const int j0 = jh*4096 + t*128;
    const float* x2jb = sx2j + (t&1)*128;

    #pragma unroll
    for (int jb=0;jb<8;++jb){
      float4 xj2 = *(const float4*)&x2jb[jb*16 + kg*4];
      f32x4 c = acc[jb];
      float4 dv = make_float4(x2q + xj2.x - 2.0f*c[0],
                              x2q + xj2.y - 2.0f*c[1],
                              x2q + xj2.z - 2.0f*c[2],
                              x2q + xj2.w - 2.0f*c[3]);
      float m4 = fminf(fminf(dv.x,dv.y), fminf(dv.z,dv.w));
      if (__any(m4 < g9)){
        const int jj = j0 + jb*16 + kg*4;
        kinsd2(bk, g9, pbd9, dv.x, jj);
        kinsd2(bk, g9, pbd9, dv.y, jj+1);
        kinsd2(bk, g9, pbd9, dv.z, jj+2);
        kinsd2(bk, g9, pbd9, dv.w, jj+3);
      }
      if (jb & 1){
        float d9 = (float)bk[9];
        float m  = fminf(d9, __shfl_xor(d9, 16));
        float mm = fminf(m,  __shfl_xor(m, 32));
        pbd9 = mm;
        g9 = mm;
      }
    }
  }

  __syncthreads();
  #pragma unroll
  for (int u=0;u<10;++u) lst[(size_t)(w*16 + lm)*40 + kg*10 + u] = bk[u];
  __syncthreads();
  if (tid < 64) {
    const double* row = &lst[(size_t)tid*40];
    int i0=0, i1=0, i2=0, i3=0;
    size_t base = ((size_t)jh*(4*NPTS) + bbase + q0 + tid)*10;
    #pragma unroll
    for (int u=0;u<10;++u){
      double ka = row[i0], kb2 = row[10+i1], kc2 = row[20+i2], kd2 = row[30+i3];
      bool tab = ka  < kb2; double mab = tab ? ka  : kb2;
      bool tcd = kc2 < kd2; double mcd = tcd ? kc2 : kd2;
      bool tt  = mab < mcd; double m   = tt  ? mab : mcd;
      pk[base+u] = m;
      i0 += (tt && tab)  ? 1 : 0;
      i1 += (tt && !tab) ? 1 : 0;
      i2 += (!tt && tcd) ? 1 : 0;
      i3 += (!tt && !tcd)? 1 : 0;
    }
  }
}

// ---------- KNN conv1 (R8): C=4, lane-local scan, 1 barrier/tile.
// Lane owns query (w*16+lm); kg-lane scans rows jb*16+kg*4+r of a [256][4] xj
// tile (double-buffered LDS via gl_lds). Distance fmaf chain identical to the
// old kernel -> bit-identical d -> identical selection. Top-10/merge == knn64.
__global__ __launch_bounds__(256, 4) void knn4_kernel(const float* __restrict__ X,
                                                      const float* __restrict__ sqn,
                                                      double* __restrict__ pk){
  __shared__ __align__(16) unsigned char smem[20480];
  // [0,4096) xj buf0 [256][4] f32 ; [4096,8192) buf1 ; [8192,10240) sx2j [2][256]
  // merge overlay: lst [64][40] f64 at offset 0
  double* lst = (double*)smem;

  const int b   = blockIdx.y;
  const int q0  = blockIdx.x * 64;
  const int jh  = blockIdx.z;
  const int tid = threadIdx.x;
  const int L   = tid & 63;
  const int w   = tid >> 6;
  const int lm  = L & 15;
  const int kg  = L >> 4;

  const size_t bbase = (size_t)b * NPTS;
  const int qi = q0 + w*16 + lm;
  const float4 q4 = *(const float4*)(X + (bbase + qi)*4);
  const float x2q = sqn[bbase + qi];

  const char* srcj  = (const char*)(X + (bbase + (size_t)jh*4096)*4);
  const float* srcs = sqn + bbase + jh*4096;

  // prologue: stage tile 0 (256 rows x 16B; wave w stages rows w*64..w*64+63)
  gl_lds16(srcj + (size_t)(w*64 + L)*16, smem + w*1024);
  gl_lds4 (srcs + w*64 + L, smem + 8192 + w*256);

  double bk[10];
  float g9 = INFINITY, pbd9 = INFINITY;
  #pragma unroll
  for (int u=0;u<10;++u) bk[u] = (double)INFINITY;

  for (int t = 0; t < 16; ++t) {
    __syncthreads();   // stage(t) landed (own vmcnt drained by syncthreads)
    if (t < 15){
      const int nb = (t+1)&1;
      gl_lds16(srcj + (size_t)(t+1)*4096 + (size_t)(w*64 + L)*16, smem + nb*4096 + w*1024);
      gl_lds4 (srcs + (t+1)*256 + w*64 + L, smem + 8192 + nb*1024 + w*256);
    }
    const float* xj  = (const float*)(smem + (t&1)*4096);
    const float* x2j = (const float*)(smem + 8192 + (t&1)*1024);
    const int j0 = jh*4096 + t*256;

    #pragma unroll
    for (int jb=0;jb<16;++jb){
      const int r0 = jb*16 + kg*4;
      float d0,d1,d2,d3;
      {
        float4 xv = *(const float4*)&xj[(r0+0)*4];
        float acc = fmaf(q4.x, xv.x, 0.f); acc = fmaf(q4.y, xv.y, acc);
        acc = fmaf(q4.z, xv.z, acc);       acc = fmaf(q4.w, xv.w, acc);
        d0 = x2q + x2j[r0+0] - 2.f*acc;
      }
      {
        float4 xv = *(const float4*)&xj[(r0+1)*4];
        float acc = fmaf(q4.x, xv.x, 0.f); acc = fmaf(q4.y, xv.y, acc);
        acc = fmaf(q4.z, xv.z, acc);       acc = fmaf(q4.w, xv.w, acc);
        d1 = x2q + x2j[r0+1] - 2.f*acc;
      }
      {
        float4 xv = *(const float4*)&xj[(r0+2)*4];
        float acc = fmaf(q4.x, xv.x, 0.f); acc = fmaf(q4.y, xv.y, acc);
        acc = fmaf(q4.z, xv.z, acc);       acc = fmaf(q4.w, xv.w, acc);
        d2 = x2q + x2j[r0+2] - 2.f*acc;
      }
      {
        float4 xv = *(const float4*)&xj[(r0+3)*4];
        float acc = fmaf(q4.x, xv.x, 0.f); acc = fmaf(q4.y, xv.y, acc);
        acc = fmaf(q4.z, xv.z, acc);       acc = fmaf(q4.w, xv.w, acc);
        d3 = x2q + x2j[r0+3] - 2.f*acc;
      }
      float m4 = fminf(fminf(d0,d1), fminf(d2,d3));
      if (__any(m4 < g9)){
        const int jj = j0 + r0;
        kinsd2(bk, g9, pbd9, d0, jj);
        kinsd2(bk, g9, pbd9, d1, jj+1);
        kinsd2(bk, g9, pbd9, d2, jj+2);
        kinsd2(bk, g9, pbd9, d3, jj+3);
      }
      if (jb & 1){
        float d9 = (float)bk[9];
        float m  = fminf(d9, __shfl_xor(d9, 16));
        float mm = fminf(m,  __shfl_xor(m, 32));
        pbd9 = mm;
        g9 = mm;
      }
    }
  }

  __syncthreads();
  #pragma unroll
  for (int u=0;u<10;++u) lst[(size_t)(w*16 + lm)*40 + kg*10 + u] = bk[u];
  __syncthreads();
  if (tid < 64) {
    const double* row = &lst[(size_t)tid*40];
    int i0=0, i1=0, i2=0, i3=0;
    size_t base = ((size_t)jh*(4*NPTS) + bbase + q0 + tid)*10;
    #pragma unroll
    for (int u=0;u<10;++u){
      double ka = row[i0], kb2 = row[10+i1], kc2 = row[20+i2], kd2 = row[30+i3];
      bool tab = ka  < kb2; double mab = tab ? ka  : kb2;
      bool tcd = kc2 < kd2; double mcd = tcd ? kc2 : kd2;
      bool tt  = mab < mcd; double m   = tt  ? mab : mcd;
      pk[base+u] = m;
      i0 += (tt && tab)  ? 1 : 0;
      i1 += (tt && !tab) ? 1 : 0;
      i2 += (!tt && tcd) ? 1 : 0;
      i3 += (!tt && !tcd)? 1 : 0;
    }
  }
}

// ---------- merge the 2 j-half partial f64-key lists -> final idx ----------
__global__ __launch_bounds__(256) void knnmerge_kernel(const double* __restrict__ pk,
                                                       int* __restrict__ idxout){
  int p = blockIdx.x*256 + threadIdx.x;   // 0..32767
  const double* A = pk + (size_t)p*10;
  const double* B = pk + (size_t)(4*NPTS)*10 + (size_t)p*10;
  int ia=0, ib=0;
  int* op = idxout + (size_t)p*10;
  #pragma unroll
  for (int u=0;u<10;++u){
    double ka = A[ia], kb = B[ib];
    bool t = ka < kb;
    op[u] = (int)(__double_as_longlong(t ? ka : kb) & 8191LL);
    ia += t ? 1 : 0; ib += t ? 0 : 1;
  }
}

// ---------- prep U/D for 64-ch edge conv (wave-per-point, lane-per-output) ----------
__global__ __launch_bounds__(256) void prepUD64_kernel(const float* __restrict__ XC, int cin,
                                                       const float* __restrict__ W,
                                                       float* __restrict__ U,
                                                       float* __restrict__ D){
  const int tid = threadIdx.x;
  const int w = tid >> 6, o = tid & 63;
  const int p = blockIdx.x*4 + w;
  const float* xr = XC + (size_t)p*192 + cin;   // wave-uniform base
  float zu = 0.f, zd = 0.f;
  #pragma unroll
  for (int c=0;c<64;++c){
    float xc = xr[c];                  // uniform across the wave
    float wt = W[c*64 + o];
    float wb = W[(64+c)*64 + o];
    zu = fmaf(xc, wt, zu);
    zd = fmaf(xc, wb - wt, zd);
  }
  U[(size_t)p*64 + o] = zu;
  D[(size_t)p*64 + o] = zd;
}

// ---------- prep U/D for conv1 ----------
__global__ __launch_bounds__(256) void prepUD12_kernel(const float* __restrict__ T,
                                                       const float* __restrict__ W1,
                                                       float* __restrict__ U,
                                                       float* __restrict__ D){
  int p = blockIdx.x*256 + threadIdx.x;
  float t[3] = {T[p*3+0], T[p*3+1], T[p*3+2]};
  const float4* W = (const float4*)W1;
  float4 u[16], q[16];
  #pragma unroll
  for (int o=0;o<16;++o){ u[o]=make_float4(0,0,0,0); q[o]=make_float4(0,0,0,0); }
  #pragma unroll
  for (int c=0;c<3;++c){
    const float tc = t[c];
    #pragma unroll
    for (int o=0;o<16;++o){
      float4 ws  = W[c*16+o],     ws2 = W[(c+3)*16+o];
      float4 wq  = W[(c+6)*16+o], wq2 = W[(c+9)*16+o];
      u[o] = f4fma(tc, make_float4(ws.x+ws2.x, ws.y+ws2.y, ws.z+ws2.z, ws.w+ws2.w), u[o]);
      q[o] = f4fma(tc, make_float4(wq.x+wq2.x, wq.y+wq2.y, wq.z+wq2.z, wq.w+wq2.w), q[o]);
    }
  }
  float4* up = (float4*)(U + (size_t)p*64);
  float4* dp = (float4*)(D + (size_t)p*64);
  #pragma unroll
  for (int o=0;o<16;++o){
    up[o] = u[o];
    dp[o] = make_float4(q[o].x-u[o].x, q[o].y-u[o].y, q[o].z-u[o].z, q[o].w-u[o].w);
  }
}

// ---------- two-layer edge conv + fused sqnorm + fused bf16 hi/lo split ----------
__global__ __launch_bounds__(256) void edge2w_kernel(const float* __restrict__ U,
                                                     const float* __restrict__ Dp,
                                                     const int* __restrict__ idx,
                                                     const float* __restrict__ Wb,
                                                     const float* __restrict__ PA, int paa, int pab,
                                                     float* __restrict__ out, int coff,
                                                     float* __restrict__ sqnout,
                                                     unsigned short* __restrict__ Xh,
                                                     unsigned short* __restrict__ Xl){
  __shared__ __align__(16) float sh[4][10][68];
  const int tid = threadIdx.x;
  const int w = tid >> 6, o = tid & 63;
  const int p = blockIdx.x*4 + w, b = p >> 13;
  const float aa = PA[paa], ab = PA[pab];

  float wreg[64];
  #pragma unroll
  for (int c=0;c<64;++c) wreg[c] = Wb[c*64 + o];

  const float dc = Dp[(size_t)p*64 + o];

  #pragma unroll
  for (int k=0;k<10;++k){
    int nb = idx[p*10 + k];
    float u = U[((size_t)(b<<13)+nb)*64 + o];
    sh[w][k][o] = preluf(u + dc, aa);
  }
  __syncthreads();

  float mx = -INFINITY;
  #pragma unroll 2
  for (int k=0;k<10;++k){
    float a0=0.f,a1=0.f,a2=0.f,a3=0.f;
    #pragma unroll
    for (int c4=0;c4<16;++c4){
      float4 hv = *(const float4*)&sh[w][k][c4*4];
      a0 = fmaf(hv.x, wreg[c4*4+0], a0);
      a1 = fmaf(hv.y, wreg[c4*4+1], a1);
      a2 = fmaf(hv.z, wreg[c4*4+2], a2);
      a3 = fmaf(hv.w, wreg[c4*4+3], a3);
    }
    float z = (a0+a1)+(a2+a3);
    mx = fmaxf(mx, preluf(z, ab));
  }
  out[(size_t)p*192 + coff + o] = mx;
  // fused bf16 hi/lo split of the output (feeds next conv's KNN GEMM)
  {
    unsigned um = __float_as_uint(mx);
    unsigned h  = (um + 0x7FFFu + ((um>>16)&1u)) & 0xFFFF0000u;
    float rr = mx - __uint_as_float(h);
    unsigned ur = __float_as_uint(rr);
    unsigned l  = (ur + 0x7FFFu + ((ur>>16)&1u)) >> 16;
    Xh[(size_t)p*64 + o] = (unsigned short)(h >> 16);
    Xl[(size_t)p*64 + o] = (unsigned short)l;
  }
  // fused sqnorm of this 64-col output row
  float sq = mx*mx;
  #pragma unroll
  for (int off=1; off<64; off<<=1) sq += __shfl_xor(sq, off);
  if (o == 0) sqnout[p] = sq;
}

// ---------- single-layer edge conv (conv3), wave-per-point ----------
__global__ __launch_bounds__(256) void edge1w_kernel(const float* __restrict__ U,
                                                     const float* __restrict__ Dp,
                                                     const int* __restrict__ idx,
                                                     const float* __restrict__ PA, int paa,
                                                     float* __restrict__ out, int coff){
  const int tid = threadIdx.x;
  const int w = tid >> 6, o = tid & 63;
  const int p = blockIdx.x*4 + w, b = p >> 13;
  const float aa = PA[paa];
  const float dc = Dp[(size_t)p*64 + o];
  float mx = -INFINITY;
  #pragma unroll
  for (int k=0;k<10;++k){
    int nb = idx[p*10 + k];
    float u = U[((size_t)(b<<13)+nb)*64 + o];
    mx = fmaxf(mx, preluf(u + dc, aa));
  }
  out[(size_t)p*192 + coff + o] = mx;
}

// ---------- fused weight prep: all four head weights -> hi/lo transposed ----------
__global__ __launch_bounds__(256) void prepWall_kernel(const float* __restrict__ W6,
                                                       const float* __restrict__ W7,
                                                       const float* __restrict__ W8,
                                                       const float* __restrict__ W9,
                                                       unsigned short* __restrict__ Wh6, unsigned short* __restrict__ Wl6,
                                                       unsigned short* __restrict__ Wh7, unsigned short* __restrict__ Wl7,
                                                       unsigned short* __restrict__ Wh8, unsigned short* __restrict__ Wl8,
                                                       unsigned short* __restrict__ Wh9, unsigned short* __restrict__ Wl9){
  int bb = blockIdx.x;
  const float* W; unsigned short *Wh, *Wl; int K, N, k;
  if (bb < 192)      { W=W6; Wh=Wh6; Wl=Wl6; K=192; N=1024; k=bb; }
  else if (bb < 384) { W=W7; Wh=Wh7; Wl=Wl7; K=192; N=256;  k=bb-192; }
  else if (bb < 640) { W=W8; Wh=Wh8; Wl=Wl8; K=256; N=256;  k=bb-384; }
  else               { W=W9; Wh=Wh9; Wl=Wl9; K=256; N=128;  k=bb-640; }
  for (int n = threadIdx.x; n < N; n += 256){
    float v = W[(size_t)k*N + n];
    unsigned ua = __float_as_uint(v);
    unsigned h = (ua + 0x7FFFu + ((ua>>16)&1u)) & 0xFFFF0000u;
    float r = v - __uint_as_float(h);
    unsigned ub = __float_as_uint(r);
    unsigned l = (ub + 0x7FFFu + ((ub>>16)&1u)) >> 16;
    Wh[(size_t)n*K + k] = (unsigned short)(h >> 16);
    Wl[(size_t)n*K + k] = (unsigned short)l;
  }
}

// ---------- MFMA bf16 hi/lo GEMM: C = prelu(A@W [+bias]); EPI2: colmax partials ----------
template<int EPI>
__global__ __launch_bounds__(256, 2) void mgemm_kernel(const float* __restrict__ A, int lda,
                                                       const unsigned short* __restrict__ WhT,
                                                       const unsigned short* __restrict__ WlT,
                                                       int K,
                                                       float* __restrict__ C, int ldc,
                                                       const float* __restrict__ bias,
                                                       const float* __restrict__ PA, int pidx,
                                                       int Ntot){
  __shared__ __align__(16) unsigned char smem[73728];
  unsigned short* sa = (unsigned short*)smem;
  unsigned short* sb = (unsigned short*)(smem + 36864);
  float* cst = (float*)smem;

  const int tid = threadIdx.x;
  const int m0 = blockIdx.x*128, n0 = blockIdx.y*128;
  const int L = tid & 63, w = tid >> 6;
  const int lm = L & 15, kg = L >> 4;

  f32x4 acc[2][8];
  #pragma unroll
  for (int mt=0;mt<2;++mt)
    #pragma unroll
    for (int nt=0;nt<8;++nt) acc[mt][nt] = (f32x4){0.f,0.f,0.f,0.f};

  for (int c0 = 0; c0 < K; c0 += 64) {
    __syncthreads();
    #pragma unroll
    for (int s=0;s<8;++s){
      int e = tid + s*256;
      int r = e >> 4, kq = (e & 15) << 2;
      float4 v = *(const float4*)(A + (size_t)(m0+r)*lda + c0 + kq);
      unsigned lo01, lo23;
      unsigned hi01 = bfsplit2(v.x, v.y, lo01);
      unsigned hi23 = bfsplit2(v.z, v.w, lo23);
      uint2 hp; hp.x = hi01; hp.y = hi23;
      uint2 lp; lp.x = lo01; lp.y = lo23;
      *(uint2*)&sa[r*72 + kq]        = hp;
      *(uint2*)&sa[9216 + r*72 + kq] = lp;
    }
    #pragma unroll
    for (int s=0;s<4;++s){
      int e = tid + s*256;
      int col = e >> 3, ko = (e & 7) << 3;
      *(uint4*)&sb[col*72 + ko]        = *(const uint4*)&WhT[(size_t)(n0+col)*K + c0 + ko];
      *(uint4*)&sb[9216 + col*72 + ko] = *(const uint4*)&WlT[(size_t)(n0+col)*K + c0 + ko];
    }
    __syncthreads();

    #pragma unroll
    for (int kc=0;kc<2;++kc){
      const int ko = kc*32 + kg*8;
      bf16x8s ah[2], al[2];
      #pragma unroll
      for (int mt=0;mt<2;++mt){
        int q = w*32 + mt*16 + lm;
        ah[mt] = *(const bf16x8s*)&sa[q*72 + ko];
        al[mt] = *(const bf16x8s*)&sa[9216 + q*72 + ko];
      }
      #pragma unroll
      for (int nt=0;nt<8;++nt){
        int n = nt*16 + lm;
        bf16x8s bh = *(const bf16x8s*)&sb[n*72 + ko];
        bf16x8s bl = *(const bf16x8s*)&sb[9216 + n*72 + ko];
        #pragma unroll
        for (int mt=0;mt<2;++mt){
          acc[mt][nt] = __builtin_amdgcn_mfma_f32_16x16x32_bf16(ah[mt], bh, acc[mt][nt], 0,0,0);
          acc[mt][nt] = __builtin_amdgcn_mfma_f32_16x16x32_bf16(ah[mt], bl, acc[mt][nt], 0,0,0);
          acc[mt][nt] = __builtin_amdgcn_mfma_f32_16x16x32_bf16(al[mt], bh, acc[mt][nt], 0,0,0);
        }
      }
    }
  }
  __syncthreads();

  const float a = PA[pidx];
  if (EPI == 2) {
    #pragma unroll
    for (int nt=0;nt<8;++nt){
      f32x4 c0v = acc[0][nt], c1v = acc[1][nt];
      float m = -INFINITY;
      #pragma unroll
      for (int r=0;r<4;++r){ m = fmaxf(m, preluf(c0v[r], a)); m = fmaxf(m, preluf(c1v[r], a)); }
      m = fmaxf(m, __shfl_xor(m, 16));
      m = fmaxf(m, __shfl_xor(m, 32));
      if (kg == 0) cst[w*128 + nt*16 + lm] = m;
    }
    __syncthreads();
    if (tid < 128){
      float m = fmaxf(fmaxf(cst[tid], cst[128+tid]), fmaxf(cst[256+tid], cst[384+tid]));
      C[(size_t)blockIdx.x*Ntot + n0 + tid] = m;
    }
  } else {
    float bc[8];
    if (EPI == 1){
      int bb = m0 >> 13;
      #pragma unroll
      for (int nt=0;nt<8;++nt) bc[nt] = bias[bb*256 + n0 + nt*16 + lm];
    }
    #pragma unroll
    for (int mt=0;mt<2;++mt){
      #pragma unroll
      for (int nt=0;nt<8;++nt){
        f32x4 c = acc[mt][nt];
        int col = nt*16 + lm;
        #pragma unroll
        for (int r=0;r<4;++r){
          int row = w*32 + mt*16 + kg*4 + r;
          float v = c[r] + (EPI==1 ? bc[nt] : 0.f);
          cst[row*132 + col] = preluf(v, a);
        }
      }
    }
    __syncthreads();
    const int tm = tid & 15, tn = tid >> 4;
    #pragma unroll
    for (int i=0;i<8;++i){
      int row = tm*8 + i;
      float4 v0 = *(const float4*)&cst[row*132 + tn*8];
      float4 v1 = *(const float4*)&cst[row*132 + tn*8 + 4];
      float* cp = C + (size_t)(m0 + row)*ldc + n0 + tn*8;
      *(float4*)cp     = v0;
      *(float4*)(cp+4) = v1;
    }
  }
}

__global__ __launch_bounds__(256) void reduce_pmax(const float* __restrict__ pmax,
                                                   float* __restrict__ x5m){
  int t = blockIdx.x*256 + threadIdx.x;
  if (t < 4096) {
    int b = t >> 10, o = t & 1023;
    float m = -INFINITY;
    for (int mt=0; mt<64; ++mt) m = fmaxf(m, pmax[((size_t)(b*64+mt))*1024 + o]);
    x5m[t] = m;
  }
}

__global__ __launch_bounds__(256) void bias7_kernel(const float* __restrict__ x5m,
                                                    const float* __restrict__ W7,
                                                    float* __restrict__ b7){
  int b = blockIdx.x; int o = threadIdx.x;
  float s = 0.f;
  for (int j=0;j<1024;++j) s = fmaf(x5m[b*1024+j], W7[(size_t)(192+j)*256 + o], s);
  b7[b*256+o] = s;
}

__global__ __launch_bounds__(256) void final10_kernel(const float* __restrict__ y3,
                                                      const float* __restrict__ W10,
                                                      const float* __restrict__ PA,
                                                      float* __restrict__ out){
  int p = blockIdx.x*256 + threadIdx.x;
  const float4* r = (const float4*)(y3 + (size_t)p*128);
  float s0=0.f, s1=0.f;
  #pragma unroll
  for (int c4=0;c4<32;++c4){
    float4 v = r[c4];
    s0 = fmaf(v.x, W10[(c4*4+0)*2+0], s0); s1 = fmaf(v.x, W10[(c4*4+0)*2+1], s1);
    s0 = fmaf(v.y, W10[(c4*4+1)*2+0], s0); s1 = fmaf(v.y, W10[(c4*4+1)*2+1], s1);
    s0 = fmaf(v.z, W10[(c4*4+2)*2+0], s0); s1 = fmaf(v.z, W10[(c4*4+2)*2+1], s1);
    s0 = fmaf(v.w, W10[(c4*4+3)*2+0], s0); s1 = fmaf(v.w, W10[(c4*4+3)*2+1], s1);
  }
  float a = PA[9];
  out[p*2+0] = s0>=0.f? s0 : a*s0;
  out[p*2+1] = s1>=0.f? s1 : a*s1;
}

extern "C" void kernel_launch(void* const* d_in, const int* in_sizes, int n_in,
                              void* d_out, int out_size, void* d_ws, size_t ws_size,
                              hipStream_t stream) {
  const float* T   = (const float*)d_in[0];
  const float* W1  = (const float*)d_in[1];
  const float* W2  = (const float*)d_in[2];
  const float* W3  = (const float*)d_in[3];
  const float* W4  = (const float*)d_in[4];
  const float* W5  = (const float*)d_in[5];
  const float* W6  = (const float*)d_in[6];
  const float* W7  = (const float*)d_in[7];
  const float* W8  = (const float*)d_in[8];
  const float* W9  = (const float*)d_in[9];
  const float* W10 = (const float*)d_in[10];
  const float* PA  = (const float*)d_in[11];

  float* ws   = (float*)d_ws;
  float* x0   = ws + 0;                // 131072
  float* sqn0 = ws + 131072;           // 32768
  float* sqn1 = ws + 163840;           // 32768
  float* sqn2 = ws + 196608;           // 32768
  int*   idx0 = (int*)(ws + 229376);   // 327680
  int*   idx1 = (int*)(ws + 557056);   // 327680
  int*   idx2 = (int*)(ws + 884736);   // 327680
  float* xcat = ws + 1212416;          // 6291456  [B,N,192]
  float* pmax = ws + 7503872;          // 262144
  float* x5m  = ws + 7766016;          // 4096
  float* b7   = ws + 7770112;          // 1024
  float* y1   = ws + 7771136;          // 8388608 floats (aliased: U / pk / Xh / Xl)
  float* y2   = ws + 16159744;         // 8388608  (aliased: D)
  float* y3   = xcat;
  float* U    = y1;                            // [32768][64] f32 = 2M floats
  float* D    = y2;
  double* pk  = (double*)y1;                   // [2][32768][10] f64 = 1.31M floats
  unsigned short* Xh = (unsigned short*)(y1 + 3145728);  // 4 MB, floats [3.0M,4.0M)
  unsigned short* Xl = (unsigned short*)(y1 + 4194304);  // 4 MB, floats [4.0M,5.0M)

  // split/transposed weights: reuse idx region (dead after edge1w)
  unsigned short* wsc = (unsigned short*)(ws + 229376);
  unsigned short* Wh6 = wsc;
  unsigned short* Wl6 = wsc + 196608;
  unsigned short* Wh7 = wsc + 393216;
  unsigned short* Wl7 = wsc + 442368;
  unsigned short* Wh8 = wsc + 491520;
  unsigned short* Wl8 = wsc + 557056;
  unsigned short* Wh9 = wsc + 622592;
  unsigned short* Wl9 = wsc + 655360;

  // conv1
  prep0_kernel<<<128, 256, 0, stream>>>(T, x0, sqn0);
  knn4_kernel<<<dim3(128,4,2), 256, 0, stream>>>(x0, sqn0, pk);
  knnmerge_kernel<<<128, 256, 0, stream>>>(pk, idx0);
  prepUD12_kernel<<<128, 256, 0, stream>>>(T, W1, U, D);
  edge2w_kernel<<<8192, 256, 0, stream>>>(U, D, idx0, W2, PA, 0, 1, xcat, 0, sqn1, Xh, Xl);

  // conv2
  knn64_kernel<<<dim3(128,4,2), 256, 0, stream>>>(Xh, Xl, sqn1, pk);
  knnmerge_kernel<<<128, 256, 0, stream>>>(pk, idx1);
  prepUD64_kernel<<<8192, 256, 0, stream>>>(xcat, 0, W3, U, D);
  edge2w_kernel<<<8192, 256, 0, stream>>>(U, D, idx1, W4, PA, 2, 3, xcat, 64, sqn2, Xh, Xl);

  // conv3
  knn64_kernel<<<dim3(128,4,2), 256, 0, stream>>>(Xh, Xl, sqn2, pk);
  knnmerge_kernel<<<128, 256, 0, stream>>>(pk, idx2);
  prepUD64_kernel<<<8192, 256, 0, stream>>>(xcat, 64, W5, U, D);
  edge1w_kernel<<<8192, 256, 0, stream>>>(U, D, idx2, PA, 4, xcat, 128);

  // head weights -> bf16 hi/lo transposed (one fused launch)
  prepWall_kernel<<<896, 256, 0, stream>>>(W6, W7, W8, W9,
                                           Wh6, Wl6, Wh7, Wl7, Wh8, Wl8, Wh9, Wl9);

  // head
  mgemm_kernel<2><<<dim3(256,8), 256, 0, stream>>>(xcat, 192, Wh6, Wl6, 192, pmax, 0, nullptr, PA, 5, 1024);
  reduce_pmax<<<16, 256, 0, stream>>>(pmax, x5m);
  bias7_kernel<<<4, 256, 0, stream>>>(x5m, W7, b7);
  mgemm_kernel<1><<<dim3(256,2), 256, 0, stream>>>(xcat, 192, Wh7, Wl7, 192, y1, 256, b7, PA, 6, 0);
  mgemm_kernel<0><<<dim3(256,2), 256, 0, stream>>>(y1, 256, Wh8, Wl8, 256, y2, 256, nullptr, PA, 7, 0);
  mgemm_kernel<0><<<dim3(256,1), 256, 0, stream>>>(y2, 256, Wh9, Wl9, 256, y3, 128, nullptr, PA, 8, 0);
  final10_kernel<<<128, 256, 0, stream>>>(y3, W10, PA, (float*)d_out);
}

// Round 9
// 1332.724 us; speedup vs baseline: 1.1430x; 1.1380x over previous
//
#include <hip/hip_runtime.h>
#include <math.h>

#define NPTS 8192
#define KNNK 10

typedef __attribute__((ext_vector_type(8))) short bf16x8s;
typedef __attribute__((ext_vector_type(4))) float f32x4;

__device__ __forceinline__ float preluf(float v, float a){ return v >= 0.f ? v : a*v; }
__device__ __forceinline__ float4 f4fma(float a, float4 b, float4 c){
  return make_float4(fmaf(a,b.x,c.x), fmaf(a,b.y,c.y), fmaf(a,b.z,c.z), fmaf(a,b.w,c.w));
}

__device__ __forceinline__ void gl_lds16(const void* g, void* l){
  __builtin_amdgcn_global_load_lds((const __attribute__((address_space(1))) void*)g,
                                   (__attribute__((address_space(3))) void*)l, 16, 0, 0);
}
__device__ __forceinline__ void gl_lds4(const void* g, void* l){
  __builtin_amdgcn_global_load_lds((const __attribute__((address_space(1))) void*)g,
                                   (__attribute__((address_space(3))) void*)l, 4, 0, 0);
}

// f64 lex key: double(d) with j OR'd into the 29 zero low-mantissa bits.
// Raw sorted-10 ladder insert (no gate): INF-padded inserts fall off the end.
__device__ __forceinline__ void kins_raw(double* bk, double t){
  #pragma unroll
  for (int s=0;s<10;++s){
    double mn = fmin(bk[s], t);
    double mx = fmax(bk[s], t);
    bk[s] = mn; t = mx;
  }
}

// Batched insert: gate d<g9 (conservative: g9 only refreshed at drains, staler =
// looser = never drops a true top-10 key). Push into 4-slot per-lane buffer
// (cheap cndmask chain); run the expensive f64 ladder only when some lane's
// buffer is full. Set semantics => final sorted-10 identical to per-candidate
// insertion. Butterfly refresh of g9 (min over the 4 kg-lanes) at each drain.
__device__ __forceinline__ void kpush(double& b0, double& b1, double& b2, double& b3,
                                      int& cnt, double* bk, float& g9, float d, int j){
  bool a = d < g9;
  if (__any(a ? 1 : 0)) {
    if (a) {
      double t = __longlong_as_double(__double_as_longlong((double)d) | (unsigned long long)(unsigned)j);
      b0 = (cnt==0) ? t : b0;
      b1 = (cnt==1) ? t : b1;
      b2 = (cnt==2) ? t : b2;
      b3 = (cnt==3) ? t : b3;
      ++cnt;
    }
    if (__any(cnt >= 4)) {
      if (__any(cnt > 0)) kins_raw(bk, b0);
      if (__any(cnt > 1)) kins_raw(bk, b1);
      if (__any(cnt > 2)) kins_raw(bk, b2);
      if (__any(cnt > 3)) kins_raw(bk, b3);
      b0 = b1 = b2 = b3 = (double)INFINITY;
      cnt = 0;
      float d9 = (float)bk[9];              // rounds back to exact d9
      float m  = fminf(d9, __shfl_xor(d9, 16));
      g9 = fminf(m, __shfl_xor(m, 32));     // min over the query's 4 scan lanes
    }
  }
}

// split float into bf16 hi/lo (rne); returns packed hi pair, sets lo pair
__device__ __forceinline__ unsigned bfsplit2(float a, float b, unsigned& lo2){
  unsigned ua = __float_as_uint(a), ub = __float_as_uint(b);
  unsigned ha = (ua + 0x7FFFu + ((ua>>16)&1u)) & 0xFFFF0000u;
  unsigned hb = (ub + 0x7FFFu + ((ub>>16)&1u)) & 0xFFFF0000u;
  float ra = a - __uint_as_float(ha);
  float rb = b - __uint_as_float(hb);
  unsigned la = __float_as_uint(ra), lb = __float_as_uint(rb);
  unsigned qa = (la + 0x7FFFu + ((la>>16)&1u)) >> 16;
  unsigned qb = (lb + 0x7FFFu + ((lb>>16)&1u)) & 0xFFFF0000u;
  lo2 = qa | qb;
  return (ha >> 16) | hb;
}

// ---------- prep: x0pad (targets padded to 4ch) + sqnorm ----------
__global__ __launch_bounds__(256) void prep0_kernel(const float* __restrict__ T,
                                                    float* __restrict__ x0,
                                                    float* __restrict__ sqn){
  int p = blockIdx.x*256 + threadIdx.x;
  float t0 = T[p*3+0], t1 = T[p*3+1], t2 = T[p*3+2];
  *(float4*)(x0 + (size_t)p*4) = make_float4(t0,t1,t2,0.f);
  float s = fmaf(t0,t0,0.f); s = fmaf(t1,t1,s); s = fmaf(t2,t2,s); s = fmaf(0.f,0.f,s);
  sqn[p] = s;
}

// ---------- KNN C=64 (R9): transposed GEMM + lane-local scan + batched inserts ----------
__global__ __launch_bounds__(256, 4) void knn64_kernel(const unsigned short* __restrict__ Xh,
                                                       const unsigned short* __restrict__ Xl,
                                                       const float* __restrict__ sqn,
                                                       double* __restrict__ pk){
  __shared__ __align__(16) unsigned char smem[33792];
  // [0,16384) xj_hi [128 j][64ch] ushort XOR-swz ; [16384,32768) xj_lo ; [32768,33792) sx2j [2][128]
  // merge overlay: lst [64 q][4][10] f64 at offset 0
  float* sx2j = (float*)(smem + 32768);
  double* lst = (double*)smem;

  const int b   = blockIdx.y;
  const int q0  = blockIdx.x * 64;
  const int jh  = blockIdx.z;          // 0..1 j-half
  const int tid = threadIdx.x;
  const int L   = tid & 63;
  const int w   = tid >> 6;            // wave owns 16 queries
  const int lm  = L & 15;
  const int kg  = L >> 4;              // 4 scan lanes per query

  const size_t bbase = (size_t)b * NPTS;
  const int qi = q0 + w*16 + lm;       // this lane's query

  bf16x8s qh[2], ql[2];
  {
    const char* Qh = (const char*)Xh + (bbase + qi)*128;
    const char* Ql = (const char*)Xl + (bbase + qi)*128;
    #pragma unroll
    for (int kc=0;kc<2;++kc){
      qh[kc] = *(const bf16x8s*)(Qh + kc*64 + kg*16);
      ql[kc] = *(const bf16x8s*)(Ql + kc*64 + kg*16);
    }
  }
  const float x2q = sqn[bbase + qi];

  const int srow = L >> 3;
  const unsigned soff = (unsigned)(((L & 7) ^ srow) << 4);
  const char* srch = (const char*)Xh + (bbase + (size_t)jh*4096 + w*32 + srow)*128 + soff;
  const char* srcl = (const char*)Xl + (bbase + (size_t)jh*4096 + w*32 + srow)*128 + soff;
  const float* sx2jsrc = sqn + bbase + jh*4096 + w*64 + L;

  #pragma unroll
  for (int i=0;i<4;++i){
    gl_lds16(srch + i*1024, smem + w*4096 + i*1024);
    gl_lds16(srcl + i*1024, smem + 16384 + w*4096 + i*1024);
  }
  if (w < 2) gl_lds4(sx2jsrc, (char*)sx2j + w*256);

  double bk[10];
  double b0 = (double)INFINITY, b1 = (double)INFINITY, b2 = (double)INFINITY, b3 = (double)INFINITY;
  int cnt = 0;
  float g9 = INFINITY;
  #pragma unroll
  for (int u=0;u<10;++u) bk[u] = (double)INFINITY;

  const char* xjh_c = (const char*)smem;
  const char* xjl_c = (const char*)smem + 16384;
  const unsigned swz = (unsigned)((lm & 7) << 4);

  for (int t = 0; t < 32; ++t) {
    __syncthreads();   // A: stage(t) landed (implicit vmcnt(0) before barrier)

    f32x4 acc[8];
    #pragma unroll
    for (int jb=0;jb<8;++jb) acc[jb] = (f32x4){0.f,0.f,0.f,0.f};

    #pragma unroll
    for (int kc=0;kc<2;++kc){
      const unsigned koff = (unsigned)(kc*64 + kg*16) ^ swz;
      #pragma unroll
      for (int jb=0;jb<8;++jb){
        const int rb = (jb*16 + lm)*128;
        bf16x8s jhf = *(const bf16x8s*)(xjh_c + rb + koff);
        bf16x8s jlf = *(const bf16x8s*)(xjl_c + rb + koff);
        acc[jb] = __builtin_amdgcn_mfma_f32_16x16x32_bf16(jhf, qh[kc], acc[jb], 0,0,0);
        acc[jb] = __builtin_amdgcn_mfma_f32_16x16x32_bf16(jlf, qh[kc], acc[jb], 0,0,0);
        acc[jb] = __builtin_amdgcn_mfma_f32_16x16x32_bf16(jhf, ql[kc], acc[jb], 0,0,0);
      }
    }
    __syncthreads();   // B: all waves done reading xj(t) -> safe to overwrite

    if (t < 31){
      const char* nh = srch + (size_t)(t+1)*16384;
      const char* nl = srcl + (size_t)(t+1)*16384;
      #pragma unroll
      for (int i=0;i<4;++i){
        gl_lds16(nh + i*1024, smem + w*4096 + i*1024);
        gl_lds16(nl + i*1024, smem + 16384 + w*4096 + i*1024);
      }
      if (w < 2) gl_lds4(sx2jsrc + (size_t)(t+1)*128, (char*)sx2j + ((t+1)&1)*512 + w*256);
    }

    const int j0 = jh*4096 + t*128;
    const float* x2jb = sx2j + (t&1)*128;

    #pragma unroll
    for (int jb=0;jb<8;++jb){
      float4 xj2 = *(const float4*)&x2jb[jb*16 + kg*4];
      f32x4 c = acc[jb];
      float4 dv = make_float4(x2q + xj2.x - 2.0f*c[0],
                              x2q + xj2.y - 2.0f*c[1],
                              x2q + xj2.z - 2.0f*c[2],
                              x2q + xj2.w - 2.0f*c[3]);
      float m4 = fminf(fminf(dv.x,dv.y), fminf(dv.z,dv.w));
      if (__any(m4 < g9)){
        const int jj = j0 + jb*16 + kg*4;
        kpush(b0,b1,b2,b3,cnt, bk, g9, dv.x, jj);
        kpush(b0,b1,b2,b3,cnt, bk, g9, dv.y, jj+1);
        kpush(b0,b1,b2,b3,cnt, bk, g9, dv.z, jj+2);
        kpush(b0,b1,b2,b3,cnt, bk, g9, dv.w, jj+3);
      }
    }
  }

  // final flush of partial buffers
  if (__any(cnt > 0)) kins_raw(bk, b0);
  if (__any(cnt > 1)) kins_raw(bk, b1);
  if (__any(cnt > 2)) kins_raw(bk, b2);
  if (__any(cnt > 3)) kins_raw(bk, b3);

  __syncthreads();
  #pragma unroll
  for (int u=0;u<10;++u) lst[(size_t)(w*16 + lm)*40 + kg*10 + u] = bk[u];
  __syncthreads();
  if (tid < 64) {
    const double* row = &lst[(size_t)tid*40];
    int i0=0, i1=0, i2=0, i3=0;
    size_t base = ((size_t)jh*(4*NPTS) + bbase + q0 + tid)*10;
    #pragma unroll
    for (int u=0;u<10;++u){
      double ka = row[i0], kb2 = row[10+i1], kc2 = row[20+i2], kd2 = row[30+i3];
      bool tab = ka  < kb2; double mab = tab ? ka  : kb2;
      bool tcd = kc2 < kd2; double mcd = tcd ? kc2 : kd2;
      bool tt  = mab < mcd; double m   = tt  ? mab : mcd;
      pk[base+u] = m;
      i0 += (tt && tab)  ? 1 : 0;
      i1 += (tt && !tab) ? 1 : 0;
      i2 += (!tt && tcd) ? 1 : 0;
      i3 += (!tt && !tcd)? 1 : 0;
    }
  }
}

// ---------- KNN conv1 (R9): C=4, lane-local scan, batched inserts ----------
__global__ __launch_bounds__(256, 4) void knn4_kernel(const float* __restrict__ X,
                                                      const float* __restrict__ sqn,
                                                      double* __restrict__ pk){
  __shared__ __align__(16) unsigned char smem[20480];
  // [0,4096) xj buf0 [256][4] f32 ; [4096,8192) buf1 ; [8192,10240) sx2j [2][256]
  // merge overlay: lst [64][40] f64 at offset 0
  double* lst = (double*)smem;

  const int b   = blockIdx.y;
  const int q0  = blockIdx.x * 64;
  const int jh  = blockIdx.z;
  const int tid = threadIdx.x;
  const int L   = tid & 63;
  const int w   = tid >> 6;
  const int lm  = L & 15;
  const int kg  = L >> 4;

  const size_t bbase = (size_t)b * NPTS;
  const int qi = q0 + w*16 + lm;
  const float4 q4 = *(const float4*)(X + (bbase + qi)*4);
  const float x2q = sqn[bbase + qi];

  const char* srcj  = (const char*)(X + (bbase + (size_t)jh*4096)*4);
  const float* srcs = sqn + bbase + jh*4096;

  gl_lds16(srcj + (size_t)(w*64 + L)*16, smem + w*1024);
  gl_lds4 (srcs + w*64 + L, smem + 8192 + w*256);

  double bk[10];
  double b0 = (double)INFINITY, b1 = (double)INFINITY, b2 = (double)INFINITY, b3 = (double)INFINITY;
  int cnt = 0;
  float g9 = INFINITY;
  #pragma unroll
  for (int u=0;u<10;++u) bk[u] = (double)INFINITY;

  for (int t = 0; t < 16; ++t) {
    __syncthreads();
    if (t < 15){
      const int nb = (t+1)&1;
      gl_lds16(srcj + (size_t)(t+1)*4096 + (size_t)(w*64 + L)*16, smem + nb*4096 + w*1024);
      gl_lds4 (srcs + (t+1)*256 + w*64 + L, smem + 8192 + nb*1024 + w*256);
    }
    const float* xj  = (const float*)(smem + (t&1)*4096);
    const float* x2j = (const float*)(smem + 8192 + (t&1)*1024);
    const int j0 = jh*4096 + t*256;

    #pragma unroll
    for (int jb=0;jb<16;++jb){
      const int r0 = jb*16 + kg*4;
      float d0,d1,d2,d3;
      {
        float4 xv = *(const float4*)&xj[(r0+0)*4];
        float acc = fmaf(q4.x, xv.x, 0.f); acc = fmaf(q4.y, xv.y, acc);
        acc = fmaf(q4.z, xv.z, acc);       acc = fmaf(q4.w, xv.w, acc);
        d0 = x2q + x2j[r0+0] - 2.f*acc;
      }
      {
        float4 xv = *(const float4*)&xj[(r0+1)*4];
        float acc = fmaf(q4.x, xv.x, 0.f); acc = fmaf(q4.y, xv.y, acc);
        acc = fmaf(q4.z, xv.z, acc);       acc = fmaf(q4.w, xv.w, acc);
        d1 = x2q + x2j[r0+1] - 2.f*acc;
      }
      {
        float4 xv = *(const float4*)&xj[(r0+2)*4];
        float acc = fmaf(q4.x, xv.x, 0.f); acc = fmaf(q4.y, xv.y, acc);
        acc = fmaf(q4.z, xv.z, acc);       acc = fmaf(q4.w, xv.w, acc);
        d2 = x2q + x2j[r0+2] - 2.f*acc;
      }
      {
        float4 xv = *(const float4*)&xj[(r0+3)*4];
        float acc = fmaf(q4.x, xv.x, 0.f); acc = fmaf(q4.y, xv.y, acc);
        acc = fmaf(q4.z, xv.z, acc);       acc = fmaf(q4.w, xv.w, acc);
        d3 = x2q + x2j[r0+3] - 2.f*acc;
      }
      float m4 = fminf(fminf(d0,d1), fminf(d2,d3));
      if (__any(m4 < g9)){
        const int jj = j0 + r0;
        kpush(b0,b1,b2,b3,cnt, bk, g9, d0, jj);
        kpush(b0,b1,b2,b3,cnt, bk, g9, d1, jj+1);
        kpush(b0,b1,b2,b3,cnt, bk, g9, d2, jj+2);
        kpush(b0,b1,b2,b3,cnt, bk, g9, d3, jj+3);
      }
    }
  }

  if (__any(cnt > 0)) kins_raw(bk, b0);
  if (__any(cnt > 1)) kins_raw(bk, b1);
  if (__any(cnt > 2)) kins_raw(bk, b2);
  if (__any(cnt > 3)) kins_raw(bk, b3);

  __syncthreads();
  #pragma unroll
  for (int u=0;u<10;++u) lst[(size_t)(w*16 + lm)*40 + kg*10 + u] = bk[u];
  __syncthreads();
  if (tid < 64) {
    const double* row = &lst[(size_t)tid*40];
    int i0=0, i1=0, i2=0, i3=0;
    size_t base = ((size_t)jh*(4*NPTS) + bbase + q0 + tid)*10;
    #pragma unroll
    for (int u=0;u<10;++u){
      double ka = row[i0], kb2 = row[10+i1], kc2 = row[20+i2], kd2 = row[30+i3];
      bool tab = ka  < kb2; double mab = tab ? ka  : kb2;
      bool tcd = kc2 < kd2; double mcd = tcd ? kc2 : kd2;
      bool tt  = mab < mcd; double m   = tt  ? mab : mcd;
      pk[base+u] = m;
      i0 += (tt && tab)  ? 1 : 0;
      i1 += (tt && !tab) ? 1 : 0;
      i2 += (!tt && tcd) ? 1 : 0;
      i3 += (!tt && !tcd)? 1 : 0;
    }
  }
}

// ---------- merge the 2 j-half partial f64-key lists -> final idx ----------
__global__ __launch_bounds__(256) void knnmerge_kernel(const double* __restrict__ pk,
                                                       int* __restrict__ idxout){
  int p = blockIdx.x*256 + threadIdx.x;   // 0..32767
  const double* A = pk + (size_t)p*10;
  const double* B = pk + (size_t)(4*NPTS)*10 + (size_t)p*10;
  int ia=0, ib=0;
  int* op = idxout + (size_t)p*10;
  #pragma unroll
  for (int u=0;u<10;++u){
    double ka = A[ia], kb = B[ib];
    bool t = ka < kb;
    op[u] = (int)(__double_as_longlong(t ? ka : kb) & 8191LL);
    ia += t ? 1 : 0; ib += t ? 0 : 1;
  }
}

// ---------- prep U/D for 64-ch edge conv (wave-per-point, lane-per-output) ----------
__global__ __launch_bounds__(256) void prepUD64_kernel(const float* __restrict__ XC, int cin,
                                                       const float* __restrict__ W,
                                                       float* __restrict__ U,
                                                       float* __restrict__ D){
  const int tid = threadIdx.x;
  const int w = tid >> 6, o = tid & 63;
  const int p = blockIdx.x*4 + w;
  const float* xr = XC + (size_t)p*192 + cin;   // wave-uniform base
  float zu = 0.f, zd = 0.f;
  #pragma unroll
  for (int c=0;c<64;++c){
    float xc = xr[c];                  // uniform across the wave
    float wt = W[c*64 + o];
    float wb = W[(64+c)*64 + o];
    zu = fmaf(xc, wt, zu);
    zd = fmaf(xc, wb - wt, zd);
  }
  U[(size_t)p*64 + o] = zu;
  D[(size_t)p*64 + o] = zd;
}

// ---------- prep U/D for conv1 ----------
__global__ __launch_bounds__(256) void prepUD12_kernel(const float* __restrict__ T,
                                                       const float* __restrict__ W1,
                                                       float* __restrict__ U,
                                                       float* __restrict__ D){
  int p = blockIdx.x*256 + threadIdx.x;
  float t[3] = {T[p*3+0], T[p*3+1], T[p*3+2]};
  const float4* W = (const float4*)W1;
  float4 u[16], q[16];
  #pragma unroll
  for (int o=0;o<16;++o){ u[o]=make_float4(0,0,0,0); q[o]=make_float4(0,0,0,0); }
  #pragma unroll
  for (int c=0;c<3;++c){
    const float tc = t[c];
    #pragma unroll
    for (int o=0;o<16;++o){
      float4 ws  = W[c*16+o],     ws2 = W[(c+3)*16+o];
      float4 wq  = W[(c+6)*16+o], wq2 = W[(c+9)*16+o];
      u[o] = f4fma(tc, make_float4(ws.x+ws2.x, ws.y+ws2.y, ws.z+ws2.z, ws.w+ws2.w), u[o]);
      q[o] = f4fma(tc, make_float4(wq.x+wq2.x, wq.y+wq2.y, wq.z+wq2.z, wq.w+wq2.w), q[o]);
    }
  }
  float4* up = (float4*)(U + (size_t)p*64);
  float4* dp = (float4*)(D + (size_t)p*64);
  #pragma unroll
  for (int o=0;o<16;++o){
    up[o] = u[o];
    dp[o] = make_float4(q[o].x-u[o].x, q[o].y-u[o].y, q[o].z-u[o].z, q[o].w-u[o].w);
  }
}

// ---------- two-layer edge conv + fused sqnorm + fused bf16 hi/lo split ----------
__global__ __launch_bounds__(256) void edge2w_kernel(const float* __restrict__ U,
                                                     const float* __restrict__ Dp,
                                                     const int* __restrict__ idx,
                                                     const float* __restrict__ Wb,
                                                     const float* __restrict__ PA, int paa, int pab,
                                                     float* __restrict__ out, int coff,
                                                     float* __restrict__ sqnout,
                                                     unsigned short* __restrict__ Xh,
                                                     unsigned short* __restrict__ Xl){
  __shared__ __align__(16) float sh[4][10][68];
  const int tid = threadIdx.x;
  const int w = tid >> 6, o = tid & 63;
  const int p = blockIdx.x*4 + w, b = p >> 13;
  const float aa = PA[paa], ab = PA[pab];

  float wreg[64];
  #pragma unroll
  for (int c=0;c<64;++c) wreg[c] = Wb[c*64 + o];

  const float dc = Dp[(size_t)p*64 + o];

  #pragma unroll
  for (int k=0;k<10;++k){
    int nb = idx[p*10 + k];
    float u = U[((size_t)(b<<13)+nb)*64 + o];
    sh[w][k][o] = preluf(u + dc, aa);
  }
  __syncthreads();

  float mx = -INFINITY;
  #pragma unroll 2
  for (int k=0;k<10;++k){
    float a0=0.f,a1=0.f,a2=0.f,a3=0.f;
    #pragma unroll
    for (int c4=0;c4<16;++c4){
      float4 hv = *(const float4*)&sh[w][k][c4*4];
      a0 = fmaf(hv.x, wreg[c4*4+0], a0);
      a1 = fmaf(hv.y, wreg[c4*4+1], a1);
      a2 = fmaf(hv.z, wreg[c4*4+2], a2);
      a3 = fmaf(hv.w, wreg[c4*4+3], a3);
    }
    float z = (a0+a1)+(a2+a3);
    mx = fmaxf(mx, preluf(z, ab));
  }
  out[(size_t)p*192 + coff + o] = mx;
  // fused bf16 hi/lo split of the output (feeds next conv's KNN GEMM)
  {
    unsigned um = __float_as_uint(mx);
    unsigned h  = (um + 0x7FFFu + ((um>>16)&1u)) & 0xFFFF0000u;
    float rr = mx - __uint_as_float(h);
    unsigned ur = __float_as_uint(rr);
    unsigned l  = (ur + 0x7FFFu + ((ur>>16)&1u)) >> 16;
    Xh[(size_t)p*64 + o] = (unsigned short)(h >> 16);
    Xl[(size_t)p*64 + o] = (unsigned short)l;
  }
  // fused sqnorm of this 64-col output row
  float sq = mx*mx;
  #pragma unroll
  for (int off=1; off<64; off<<=1) sq += __shfl_xor(sq, off);
  if (o == 0) sqnout[p] = sq;
}

// ---------- single-layer edge conv (conv3), wave-per-point ----------
__global__ __launch_bounds__(256) void edge1w_kernel(const float* __restrict__ U,
                                                     const float* __restrict__ Dp,
                                                     const int* __restrict__ idx,
                                                     const float* __restrict__ PA, int paa,
                                                     float* __restrict__ out, int coff){
  const int tid = threadIdx.x;
  const int w = tid >> 6, o = tid & 63;
  const int p = blockIdx.x*4 + w, b = p >> 13;
  const float aa = PA[paa];
  const float dc = Dp[(size_t)p*64 + o];
  float mx = -INFINITY;
  #pragma unroll
  for (int k=0;k<10;++k){
    int nb = idx[p*10 + k];
    float u = U[((size_t)(b<<13)+nb)*64 + o];
    mx = fmaxf(mx, preluf(u + dc, aa));
  }
  out[(size_t)p*192 + coff + o] = mx;
}

// ---------- fused weight prep: all four head weights -> hi/lo transposed ----------
__global__ __launch_bounds__(256) void prepWall_kernel(const float* __restrict__ W6,
                                                       const float* __restrict__ W7,
                                                       const float* __restrict__ W8,
                                                       const float* __restrict__ W9,
                                                       unsigned short* __restrict__ Wh6, unsigned short* __restrict__ Wl6,
                                                       unsigned short* __restrict__ Wh7, unsigned short* __restrict__ Wl7,
                                                       unsigned short* __restrict__ Wh8, unsigned short* __restrict__ Wl8,
                                                       unsigned short* __restrict__ Wh9, unsigned short* __restrict__ Wl9){
  int bb = blockIdx.x;
  const float* W; unsigned short *Wh, *Wl; int K, N, k;
  if (bb < 192)      { W=W6; Wh=Wh6; Wl=Wl6; K=192; N=1024; k=bb; }
  else if (bb < 384) { W=W7; Wh=Wh7; Wl=Wl7; K=192; N=256;  k=bb-192; }
  else if (bb < 640) { W=W8; Wh=Wh8; Wl=Wl8; K=256; N=256;  k=bb-384; }
  else               { W=W9; Wh=Wh9; Wl=Wl9; K=256; N=128;  k=bb-640; }
  for (int n = threadIdx.x; n < N; n += 256){
    float v = W[(size_t)k*N + n];
    unsigned ua = __float_as_uint(v);
    unsigned h = (ua + 0x7FFFu + ((ua>>16)&1u)) & 0xFFFF0000u;
    float r = v - __uint_as_float(h);
    unsigned ub = __float_as_uint(r);
    unsigned l = (ub + 0x7FFFu + ((ub>>16)&1u)) >> 16;
    Wh[(size_t)n*K + k] = (unsigned short)(h >> 16);
    Wl[(size_t)n*K + k] = (unsigned short)l;
  }
}

// ---------- MFMA bf16 hi/lo GEMM: C = prelu(A@W [+bias]); EPI2: colmax partials ----------
template<int EPI>
__global__ __launch_bounds__(256, 2) void mgemm_kernel(const float* __restrict__ A, int lda,
                                                       const unsigned short* __restrict__ WhT,
                                                       const unsigned short* __restrict__ WlT,
                                                       int K,
                                                       float* __restrict__ C, int ldc,
                                                       const float* __restrict__ bias,
                                                       const float* __restrict__ PA, int pidx,
                                                       int Ntot){
  __shared__ __align__(16) unsigned char smem[73728];
  unsigned short* sa = (unsigned short*)smem;
  unsigned short* sb = (unsigned short*)(smem + 36864);
  float* cst = (float*)smem;

  const int tid = threadIdx.x;
  const int m0 = blockIdx.x*128, n0 = blockIdx.y*128;
  const int L = tid & 63, w = tid >> 6;
  const int lm = L & 15, kg = L >> 4;

  f32x4 acc[2][8];
  #pragma unroll
  for (int mt=0;mt<2;++mt)
    #pragma unroll
    for (int nt=0;nt<8;++nt) acc[mt][nt] = (f32x4){0.f,0.f,0.f,0.f};

  for (int c0 = 0; c0 < K; c0 += 64) {
    __syncthreads();
    #pragma unroll
    for (int s=0;s<8;++s){
      int e = tid + s*256;
      int r = e >> 4, kq = (e & 15) << 2;
      float4 v = *(const float4*)(A + (size_t)(m0+r)*lda + c0 + kq);
      unsigned lo01, lo23;
      unsigned hi01 = bfsplit2(v.x, v.y, lo01);
      unsigned hi23 = bfsplit2(v.z, v.w, lo23);
      uint2 hp; hp.x = hi01; hp.y = hi23;
      uint2 lp; lp.x = lo01; lp.y = lo23;
      *(uint2*)&sa[r*72 + kq]        = hp;
      *(uint2*)&sa[9216 + r*72 + kq] = lp;
    }
    #pragma unroll
    for (int s=0;s<4;++s){
      int e = tid + s*256;
      int col = e >> 3, ko = (e & 7) << 3;
      *(uint4*)&sb[col*72 + ko]        = *(const uint4*)&WhT[(size_t)(n0+col)*K + c0 + ko];
      *(uint4*)&sb[9216 + col*72 + ko] = *(const uint4*)&WlT[(size_t)(n0+col)*K + c0 + ko];
    }
    __syncthreads();

    #pragma unroll
    for (int kc=0;kc<2;++kc){
      const int ko = kc*32 + kg*8;
      bf16x8s ah[2], al[2];
      #pragma unroll
      for (int mt=0;mt<2;++mt){
        int q = w*32 + mt*16 + lm;
        ah[mt] = *(const bf16x8s*)&sa[q*72 + ko];
        al[mt] = *(const bf16x8s*)&sa[9216 + q*72 + ko];
      }
      #pragma unroll
      for (int nt=0;nt<8;++nt){
        int n = nt*16 + lm;
        bf16x8s bh = *(const bf16x8s*)&sb[n*72 + ko];
        bf16x8s bl = *(const bf16x8s*)&sb[9216 + n*72 + ko];
        #pragma unroll
        for (int mt=0;mt<2;++mt){
          acc[mt][nt] = __builtin_amdgcn_mfma_f32_16x16x32_bf16(ah[mt], bh, acc[mt][nt], 0,0,0);
          acc[mt][nt] = __builtin_amdgcn_mfma_f32_16x16x32_bf16(ah[mt], bl, acc[mt][nt], 0,0,0);
          acc[mt][nt] = __builtin_amdgcn_mfma_f32_16x16x32_bf16(al[mt], bh, acc[mt][nt], 0,0,0);
        }
      }
    }
  }
  __syncthreads();

  const float a = PA[pidx];
  if (EPI == 2) {
    #pragma unroll
    for (int nt=0;nt<8;++nt){
      f32x4 c0v = acc[0][nt], c1v = acc[1][nt];
      float m = -INFINITY;
      #pragma unroll
      for (int r=0;r<4;++r){ m = fmaxf(m, preluf(c0v[r], a)); m = fmaxf(m, preluf(c1v[r], a)); }
      m = fmaxf(m, __shfl_xor(m, 16));
      m = fmaxf(m, __shfl_xor(m, 32));
      if (kg == 0) cst[w*128 + nt*16 + lm] = m;
    }
    __syncthreads();
    if (tid < 128){
      float m = fmaxf(fmaxf(cst[tid], cst[128+tid]), fmaxf(cst[256+tid], cst[384+tid]));
      C[(size_t)blockIdx.x*Ntot + n0 + tid] = m;
    }
  } else {
    float bc[8];
    if (EPI == 1){
      int bb = m0 >> 13;
      #pragma unroll
      for (int nt=0;nt<8;++nt) bc[nt] = bias[bb*256 + n0 + nt*16 + lm];
    }
    #pragma unroll
    for (int mt=0;mt<2;++mt){
      #pragma unroll
      for (int nt=0;nt<8;++nt){
        f32x4 c = acc[mt][nt];
        int col = nt*16 + lm;
        #pragma unroll
        for (int r=0;r<4;++r){
          int row = w*32 + mt*16 + kg*4 + r;
          float v = c[r] + (EPI==1 ? bc[nt] : 0.f);
          cst[row*132 + col] = preluf(v, a);
        }
      }
    }
    __syncthreads();
    const int tm = tid & 15, tn = tid >> 4;
    #pragma unroll
    for (int i=0;i<8;++i){
      int row = tm*8 + i;
      float4 v0 = *(const float4*)&cst[row*132 + tn*8];
      float4 v1 = *(const float4*)&cst[row*132 + tn*8 + 4];
      float* cp = C + (size_t)(m0 + row)*ldc + n0 + tn*8;
      *(float4*)cp     = v0;
      *(float4*)(cp+4) = v1;
    }
  }
}

__global__ __launch_bounds__(256) void reduce_pmax(const float* __restrict__ pmax,
                                                   float* __restrict__ x5m){
  int t = blockIdx.x*256 + threadIdx.x;
  if (t < 4096) {
    int b = t >> 10, o = t & 1023;
    float m = -INFINITY;
    for (int mt=0; mt<64; ++mt) m = fmaxf(m, pmax[((size_t)(b*64+mt))*1024 + o]);
    x5m[t] = m;
  }
}

__global__ __launch_bounds__(256) void bias7_kernel(const float* __restrict__ x5m,
                                                    const float* __restrict__ W7,
                                                    float* __restrict__ b7){
  int b = blockIdx.x; int o = threadIdx.x;
  float s = 0.f;
  for (int j=0;j<1024;++j) s = fmaf(x5m[b*1024+j], W7[(size_t)(192+j)*256 + o], s);
  b7[b*256+o] = s;
}

__global__ __launch_bounds__(256) void final10_kernel(const float* __restrict__ y3,
                                                      const float* __restrict__ W10,
                                                      const float* __restrict__ PA,
                                                      float* __restrict__ out){
  int p = blockIdx.x*256 + threadIdx.x;
  const float4* r = (const float4*)(y3 + (size_t)p*128);
  float s0=0.f, s1=0.f;
  #pragma unroll
  for (int c4=0;c4<32;++c4){
    float4 v = r[c4];
    s0 = fmaf(v.x, W10[(c4*4+0)*2+0], s0); s1 = fmaf(v.x, W10[(c4*4+0)*2+1], s1);
    s0 = fmaf(v.y, W10[(c4*4+1)*2+0], s0); s1 = fmaf(v.y, W10[(c4*4+1)*2+1], s1);
    s0 = fmaf(v.z, W10[(c4*4+2)*2+0], s0); s1 = fmaf(v.z, W10[(c4*4+2)*2+1], s1);
    s0 = fmaf(v.w, W10[(c4*4+3)*2+0], s0); s1 = fmaf(v.w, W10[(c4*4+3)*2+1], s1);
  }
  float a = PA[9];
  out[p*2+0] = s0>=0.f? s0 : a*s0;
  out[p*2+1] = s1>=0.f? s1 : a*s1;
}

extern "C" void kernel_launch(void* const* d_in, const int* in_sizes, int n_in,
                              void* d_out, int out_size, void* d_ws, size_t ws_size,
                              hipStream_t stream) {
  const float* T   = (const float*)d_in[0];
  const float* W1  = (const float*)d_in[1];
  const float* W2  = (const float*)d_in[2];
  const float* W3  = (const float*)d_in[3];
  const float* W4  = (const float*)d_in[4];
  const float* W5  = (const float*)d_in[5];
  const float* W6  = (const float*)d_in[6];
  const float* W7  = (const float*)d_in[7];
  const float* W8  = (const float*)d_in[8];
  const float* W9  = (const float*)d_in[9];
  const float* W10 = (const float*)d_in[10];
  const float* PA  = (const float*)d_in[11];

  float* ws   = (float*)d_ws;
  float* x0   = ws + 0;                // 131072
  float* sqn0 = ws + 131072;           // 32768
  float* sqn1 = ws + 163840;           // 32768
  float* sqn2 = ws + 196608;           // 32768
  int*   idx0 = (int*)(ws + 229376);   // 327680
  int*   idx1 = (int*)(ws + 557056);   // 327680
  int*   idx2 = (int*)(ws + 884736);   // 327680
  float* xcat = ws + 1212416;          // 6291456  [B,N,192]
  float* pmax = ws + 7503872;          // 262144
  float* x5m  = ws + 7766016;          // 4096
  float* b7   = ws + 7770112;          // 1024
  float* y1   = ws + 7771136;          // 8388608 floats (aliased: U / pk / Xh / Xl)
  float* y2   = ws + 16159744;         // 8388608  (aliased: D)
  float* y3   = xcat;
  float* U    = y1;                            // [32768][64] f32 = 2M floats
  float* D    = y2;
  double* pk  = (double*)y1;                   // [2][32768][10] f64 = 1.31M floats
  unsigned short* Xh = (unsigned short*)(y1 + 3145728);  // 4 MB, floats [3.0M,4.0M)
  unsigned short* Xl = (unsigned short*)(y1 + 4194304);  // 4 MB, floats [4.0M,5.0M)

  // split/transposed weights: reuse idx region (dead after edge1w)
  unsigned short* wsc = (unsigned short*)(ws + 229376);
  unsigned short* Wh6 = wsc;
  unsigned short* Wl6 = wsc + 196608;
  unsigned short* Wh7 = wsc + 393216;
  unsigned short* Wl7 = wsc + 442368;
  unsigned short* Wh8 = wsc + 491520;
  unsigned short* Wl8 = wsc + 557056;
  unsigned short* Wh9 = wsc + 622592;
  unsigned short* Wl9 = wsc + 655360;

  // conv1
  prep0_kernel<<<128, 256, 0, stream>>>(T, x0, sqn0);
  knn4_kernel<<<dim3(128,4,2), 256, 0, stream>>>(x0, sqn0, pk);
  knnmerge_kernel<<<128, 256, 0, stream>>>(pk, idx0);
  prepUD12_kernel<<<128, 256, 0, stream>>>(T, W1, U, D);
  edge2w_kernel<<<8192, 256, 0, stream>>>(U, D, idx0, W2, PA, 0, 1, xcat, 0, sqn1, Xh, Xl);

  // conv2
  knn64_kernel<<<dim3(128,4,2), 256, 0, stream>>>(Xh, Xl, sqn1, pk);
  knnmerge_kernel<<<128, 256, 0, stream>>>(pk, idx1);
  prepUD64_kernel<<<8192, 256, 0, stream>>>(xcat, 0, W3, U, D);
  edge2w_kernel<<<8192, 256, 0, stream>>>(U, D, idx1, W4, PA, 2, 3, xcat, 64, sqn2, Xh, Xl);

  // conv3
  knn64_kernel<<<dim3(128,4,2), 256, 0, stream>>>(Xh, Xl, sqn2, pk);
  knnmerge_kernel<<<128, 256, 0, stream>>>(pk, idx2);
  prepUD64_kernel<<<8192, 256, 0, stream>>>(xcat, 64, W5, U, D);
  edge1w_kernel<<<8192, 256, 0, stream>>>(U, D, idx2, PA, 4, xcat, 128);

  // head weights -> bf16 hi/lo transposed (one fused launch)
  prepWall_kernel<<<896, 256, 0, stream>>>(W6, W7, W8, W9,
                                           Wh6, Wl6, Wh7, Wl7, Wh8, Wl8, Wh9, Wl9);

  // head
  mgemm_kernel<2><<<dim3(256,8), 256, 0, stream>>>(xcat, 192, Wh6, Wl6, 192, pmax, 0, nullptr, PA, 5, 1024);
  reduce_pmax<<<16, 256, 0, stream>>>(pmax, x5m);
  bias7_kernel<<<4, 256, 0, stream>>>(x5m, W7, b7);
  mgemm_kernel<1><<<dim3(256,2), 256, 0, stream>>>(xcat, 192, Wh7, Wl7, 192, y1, 256, b7, PA, 6, 0);
  mgemm_kernel<0><<<dim3(256,2), 256, 0, stream>>>(y1, 256, Wh8, Wl8, 256, y2, 256, nullptr, PA, 7, 0);
  mgemm_kernel<0><<<dim3(256,1), 256, 0, stream>>>(y2, 256, Wh9, Wl9, 256, y3, 128, nullptr, PA, 8, 0);
  final10_kernel<<<128, 256, 0, stream>>>(y3, W10, PA, (float*)d_out);
}

// Round 10
// 1251.512 us; speedup vs baseline: 1.2171x; 1.0649x over previous
//
#include <hip/hip_runtime.h>
#include <math.h>

#define NPTS 8192
#define KNNK 10

typedef __attribute__((ext_vector_type(8))) short bf16x8s;
typedef __attribute__((ext_vector_type(4))) float f32x4;

__device__ __forceinline__ float preluf(float v, float a){ return v >= 0.f ? v : a*v; }
__device__ __forceinline__ float4 f4fma(float a, float4 b, float4 c){
  return make_float4(fmaf(a,b.x,c.x), fmaf(a,b.y,c.y), fmaf(a,b.z,c.z), fmaf(a,b.w,c.w));
}

__device__ __forceinline__ void gl_lds16(const void* g, void* l){
  __builtin_amdgcn_global_load_lds((const __attribute__((address_space(1))) void*)g,
                                   (__attribute__((address_space(3))) void*)l, 16, 0, 0);
}
__device__ __forceinline__ void gl_lds4(const void* g, void* l){
  __builtin_amdgcn_global_load_lds((const __attribute__((address_space(1))) void*)g,
                                   (__attribute__((address_space(3))) void*)l, 4, 0, 0);
}

// f64 lex key: double(d) with j OR'd into the 29 zero low-mantissa bits.
// Raw sorted-10 ladder insert (no gate): INF-padded inserts fall off the end.
__device__ __forceinline__ void kins_raw(double* bk, double t){
  #pragma unroll
  for (int s=0;s<10;++s){
    double mn = fmin(bk[s], t);
    double mx = fmax(bk[s], t);
    bk[s] = mn; t = mx;
  }
}

// Gate refresh across the query's 4 scan lanes (lanes lm, lm+16, lm+32, lm+48):
//   g9a = min_kg d9  : some lane holds 10 strictly-smaller keys  -> safe drop
//   g9b = max_kg d2  : every lane holds 3 strictly-smaller keys (12>10) -> safe drop
// (strictness relies on no exact f32 distance ties, same as the original gate;
//  (float)bk[u] recovers the exact f32 d since index bits sit below f32 precision)
__device__ __forceinline__ float gate_refresh(const double* bk){
  float d9 = (float)bk[9];
  float m  = fminf(d9, __shfl_xor(d9, 16));
  float g9a = fminf(m, __shfl_xor(m, 32));
  float d2 = (float)bk[2];
  float M  = fmaxf(d2, __shfl_xor(d2, 16));
  float g9b = fmaxf(M, __shfl_xor(M, 32));
  return fminf(g9a, g9b);
}

// Batched insert: conservative gate (refreshed at drains; staler = looser =
// never drops a true top-10 key). Push into 4-slot per-lane buffer (cheap
// cndmask chain); run the expensive f64 ladder only when some lane's buffer
// is full. Set semantics => final sorted-10 identical to per-candidate insert.
__device__ __forceinline__ void kpush(double& b0, double& b1, double& b2, double& b3,
                                      int& cnt, double* bk, float& g9, float d, int j){
  bool a = d < g9;
  if (__any(a ? 1 : 0)) {
    if (a) {
      double t = __longlong_as_double(__double_as_longlong((double)d) | (unsigned long long)(unsigned)j);
      b0 = (cnt==0) ? t : b0;
      b1 = (cnt==1) ? t : b1;
      b2 = (cnt==2) ? t : b2;
      b3 = (cnt==3) ? t : b3;
      ++cnt;
    }
    if (__any(cnt >= 4)) {
      if (__any(cnt > 0)) kins_raw(bk, b0);
      if (__any(cnt > 1)) kins_raw(bk, b1);
      if (__any(cnt > 2)) kins_raw(bk, b2);
      if (__any(cnt > 3)) kins_raw(bk, b3);
      b0 = b1 = b2 = b3 = (double)INFINITY;
      cnt = 0;
      g9 = gate_refresh(bk);
    }
  }
}

// split float into bf16 hi/lo (rne); returns packed hi pair, sets lo pair
__device__ __forceinline__ unsigned bfsplit2(float a, float b, unsigned& lo2){
  unsigned ua = __float_as_uint(a), ub = __float_as_uint(b);
  unsigned ha = (ua + 0x7FFFu + ((ua>>16)&1u)) & 0xFFFF0000u;
  unsigned hb = (ub + 0x7FFFu + ((ub>>16)&1u)) & 0xFFFF0000u;
  float ra = a - __uint_as_float(ha);
  float rb = b - __uint_as_float(hb);
  unsigned la = __float_as_uint(ra), lb = __float_as_uint(rb);
  unsigned qa = (la + 0x7FFFu + ((la>>16)&1u)) >> 16;
  unsigned qb = (lb + 0x7FFFu + ((lb>>16)&1u)) & 0xFFFF0000u;
  lo2 = qa | qb;
  return (ha >> 16) | hb;
}

// ---------- prep: x0pad (targets padded to 4ch) + sqnorm ----------
__global__ __launch_bounds__(256) void prep0_kernel(const float* __restrict__ T,
                                                    float* __restrict__ x0,
                                                    float* __restrict__ sqn){
  int p = blockIdx.x*256 + threadIdx.x;
  float t0 = T[p*3+0], t1 = T[p*3+1], t2 = T[p*3+2];
  *(float4*)(x0 + (size_t)p*4) = make_float4(t0,t1,t2,0.f);
  float s = fmaf(t0,t0,0.f); s = fmaf(t1,t1,s); s = fmaf(t2,t2,s); s = fmaf(0.f,0.f,s);
  sqn[p] = s;
}

// ---------- KNN C=64 (R10): transposed GEMM + lane-local scan + batched inserts
// + two-statistic gate (min-lane-d9, max-lane-d2) ----------
__global__ __launch_bounds__(256, 4) void knn64_kernel(const unsigned short* __restrict__ Xh,
                                                       const unsigned short* __restrict__ Xl,
                                                       const float* __restrict__ sqn,
                                                       double* __restrict__ pk){
  __shared__ __align__(16) unsigned char smem[33792];
  // [0,16384) xj_hi [128 j][64ch] ushort XOR-swz ; [16384,32768) xj_lo ; [32768,33792) sx2j [2][128]
  // merge overlay: lst [64 q][4][10] f64 at offset 0
  float* sx2j = (float*)(smem + 32768);
  double* lst = (double*)smem;

  const int b   = blockIdx.y;
  const int q0  = blockIdx.x * 64;
  const int jh  = blockIdx.z;          // 0..1 j-half
  const int tid = threadIdx.x;
  const int L   = tid & 63;
  const int w   = tid >> 6;            // wave owns 16 queries
  const int lm  = L & 15;
  const int kg  = L >> 4;              // 4 scan lanes per query

  const size_t bbase = (size_t)b * NPTS;
  const int qi = q0 + w*16 + lm;       // this lane's query

  bf16x8s qh[2], ql[2];
  {
    const char* Qh = (const char*)Xh + (bbase + qi)*128;
    const char* Ql = (const char*)Xl + (bbase + qi)*128;
    #pragma unroll
    for (int kc=0;kc<2;++kc){
      qh[kc] = *(const bf16x8s*)(Qh + kc*64 + kg*16);
      ql[kc] = *(const bf16x8s*)(Ql + kc*64 + kg*16);
    }
  }
  const float x2q = sqn[bbase + qi];

  const int srow = L >> 3;
  const unsigned soff = (unsigned)(((L & 7) ^ srow) << 4);
  const char* srch = (const char*)Xh + (bbase + (size_t)jh*4096 + w*32 + srow)*128 + soff;
  const char* srcl = (const char*)Xl + (bbase + (size_t)jh*4096 + w*32 + srow)*128 + soff;
  const float* sx2jsrc = sqn + bbase + jh*4096 + w*64 + L;

  #pragma unroll
  for (int i=0;i<4;++i){
    gl_lds16(srch + i*1024, smem + w*4096 + i*1024);
    gl_lds16(srcl + i*1024, smem + 16384 + w*4096 + i*1024);
  }
  if (w < 2) gl_lds4(sx2jsrc, (char*)sx2j + w*256);

  double bk[10];
  double b0 = (double)INFINITY, b1 = (double)INFINITY, b2 = (double)INFINITY, b3 = (double)INFINITY;
  int cnt = 0;
  float g9 = INFINITY;
  #pragma unroll
  for (int u=0;u<10;++u) bk[u] = (double)INFINITY;

  const char* xjh_c = (const char*)smem;
  const char* xjl_c = (const char*)smem + 16384;
  const unsigned swz = (unsigned)((lm & 7) << 4);

  for (int t = 0; t < 32; ++t) {
    __syncthreads();   // A: stage(t) landed (implicit vmcnt(0) before barrier)

    f32x4 acc[8];
    #pragma unroll
    for (int jb=0;jb<8;++jb) acc[jb] = (f32x4){0.f,0.f,0.f,0.f};

    #pragma unroll
    for (int kc=0;kc<2;++kc){
      const unsigned koff = (unsigned)(kc*64 + kg*16) ^ swz;
      #pragma unroll
      for (int jb=0;jb<8;++jb){
        const int rb = (jb*16 + lm)*128;
        bf16x8s jhf = *(const bf16x8s*)(xjh_c + rb + koff);
        bf16x8s jlf = *(const bf16x8s*)(xjl_c + rb + koff);
        acc[jb] = __builtin_amdgcn_mfma_f32_16x16x32_bf16(jhf, qh[kc], acc[jb], 0,0,0);
        acc[jb] = __builtin_amdgcn_mfma_f32_16x16x32_bf16(jlf, qh[kc], acc[jb], 0,0,0);
        acc[jb] = __builtin_amdgcn_mfma_f32_16x16x32_bf16(jhf, ql[kc], acc[jb], 0,0,0);
      }
    }
    __syncthreads();   // B: all waves done reading xj(t) -> safe to overwrite

    if (t < 31){
      const char* nh = srch + (size_t)(t+1)*16384;
      const char* nl = srcl + (size_t)(t+1)*16384;
      #pragma unroll
      for (int i=0;i<4;++i){
        gl_lds16(nh + i*1024, smem + w*4096 + i*1024);
        gl_lds16(nl + i*1024, smem + 16384 + w*4096 + i*1024);
      }
      if (w < 2) gl_lds4(sx2jsrc + (size_t)(t+1)*128, (char*)sx2j + ((t+1)&1)*512 + w*256);
    }

    const int j0 = jh*4096 + t*128;
    const float* x2jb = sx2j + (t&1)*128;

    #pragma unroll
    for (int jb=0;jb<8;++jb){
      float4 xj2 = *(const float4*)&x2jb[jb*16 + kg*4];
      f32x4 c = acc[jb];
      float4 dv = make_float4(x2q + xj2.x - 2.0f*c[0],
                              x2q + xj2.y - 2.0f*c[1],
                              x2q + xj2.z - 2.0f*c[2],
                              x2q + xj2.w - 2.0f*c[3]);
      float m4 = fminf(fminf(dv.x,dv.y), fminf(dv.z,dv.w));
      if (__any(m4 < g9)){
        const int jj = j0 + jb*16 + kg*4;
        kpush(b0,b1,b2,b3,cnt, bk, g9, dv.x, jj);
        kpush(b0,b1,b2,b3,cnt, bk, g9, dv.y, jj+1);
        kpush(b0,b1,b2,b3,cnt, bk, g9, dv.z, jj+2);
        kpush(b0,b1,b2,b3,cnt, bk, g9, dv.w, jj+3);
      }
    }
  }

  // final flush of partial buffers
  if (__any(cnt > 0)) kins_raw(bk, b0);
  if (__any(cnt > 1)) kins_raw(bk, b1);
  if (__any(cnt > 2)) kins_raw(bk, b2);
  if (__any(cnt > 3)) kins_raw(bk, b3);

  __syncthreads();
  #pragma unroll
  for (int u=0;u<10;++u) lst[(size_t)(w*16 + lm)*40 + kg*10 + u] = bk[u];
  __syncthreads();
  if (tid < 64) {
    const double* row = &lst[(size_t)tid*40];
    int i0=0, i1=0, i2=0, i3=0;
    size_t base = ((size_t)jh*(4*NPTS) + bbase + q0 + tid)*10;
    #pragma unroll
    for (int u=0;u<10;++u){
      double ka = row[i0], kb2 = row[10+i1], kc2 = row[20+i2], kd2 = row[30+i3];
      bool tab = ka  < kb2; double mab = tab ? ka  : kb2;
      bool tcd = kc2 < kd2; double mcd = tcd ? kc2 : kd2;
      bool tt  = mab < mcd; double m   = tt  ? mab : mcd;
      pk[base+u] = m;
      i0 += (tt && tab)  ? 1 : 0;
      i1 += (tt && !tab) ? 1 : 0;
      i2 += (!tt && tcd) ? 1 : 0;
      i3 += (!tt && !tcd)? 1 : 0;
    }
  }
}

// ---------- KNN conv1 (R10): C=4, lane-local scan, batched inserts + two-stat gate ----------
__global__ __launch_bounds__(256, 4) void knn4_kernel(const float* __restrict__ X,
                                                      const float* __restrict__ sqn,
                                                      double* __restrict__ pk){
  __shared__ __align__(16) unsigned char smem[20480];
  // [0,4096) xj buf0 [256][4] f32 ; [4096,8192) buf1 ; [8192,10240) sx2j [2][256]
  // merge overlay: lst [64][40] f64 at offset 0
  double* lst = (double*)smem;

  const int b   = blockIdx.y;
  const int q0  = blockIdx.x * 64;
  const int jh  = blockIdx.z;
  const int tid = threadIdx.x;
  const int L   = tid & 63;
  const int w   = tid >> 6;
  const int lm  = L & 15;
  const int kg  = L >> 4;

  const size_t bbase = (size_t)b * NPTS;
  const int qi = q0 + w*16 + lm;
  const float4 q4 = *(const float4*)(X + (bbase + qi)*4);
  const float x2q = sqn[bbase + qi];

  const char* srcj  = (const char*)(X + (bbase + (size_t)jh*4096)*4);
  const float* srcs = sqn + bbase + jh*4096;

  gl_lds16(srcj + (size_t)(w*64 + L)*16, smem + w*1024);
  gl_lds4 (srcs + w*64 + L, smem + 8192 + w*256);

  double bk[10];
  double b0 = (double)INFINITY, b1 = (double)INFINITY, b2 = (double)INFINITY, b3 = (double)INFINITY;
  int cnt = 0;
  float g9 = INFINITY;
  #pragma unroll
  for (int u=0;u<10;++u) bk[u] = (double)INFINITY;

  for (int t = 0; t < 16; ++t) {
    __syncthreads();
    if (t < 15){
      const int nb = (t+1)&1;
      gl_lds16(srcj + (size_t)(t+1)*4096 + (size_t)(w*64 + L)*16, smem + nb*4096 + w*1024);
      gl_lds4 (srcs + (t+1)*256 + w*64 + L, smem + 8192 + nb*1024 + w*256);
    }
    const float* xj  = (const float*)(smem + (t&1)*4096);
    const float* x2j = (const float*)(smem + 8192 + (t&1)*1024);
    const int j0 = jh*4096 + t*256;

    #pragma unroll
    for (int jb=0;jb<16;++jb){
      const int r0 = jb*16 + kg*4;
      float d0,d1,d2,d3;
      {
        float4 xv = *(const float4*)&xj[(r0+0)*4];
        float acc = fmaf(q4.x, xv.x, 0.f); acc = fmaf(q4.y, xv.y, acc);
        acc = fmaf(q4.z, xv.z, acc);       acc = fmaf(q4.w, xv.w, acc);
        d0 = x2q + x2j[r0+0] - 2.f*acc;
      }
      {
        float4 xv = *(const float4*)&xj[(r0+1)*4];
        float acc = fmaf(q4.x, xv.x, 0.f); acc = fmaf(q4.y, xv.y, acc);
        acc = fmaf(q4.z, xv.z, acc);       acc = fmaf(q4.w, xv.w, acc);
        d1 = x2q + x2j[r0+1] - 2.f*acc;
      }
      {
        float4 xv = *(const float4*)&xj[(r0+2)*4];
        float acc = fmaf(q4.x, xv.x, 0.f); acc = fmaf(q4.y, xv.y, acc);
        acc = fmaf(q4.z, xv.z, acc);       acc = fmaf(q4.w, xv.w, acc);
        d2 = x2q + x2j[r0+2] - 2.f*acc;
      }
      {
        float4 xv = *(const float4*)&xj[(r0+3)*4];
        float acc = fmaf(q4.x, xv.x, 0.f); acc = fmaf(q4.y, xv.y, acc);
        acc = fmaf(q4.z, xv.z, acc);       acc = fmaf(q4.w, xv.w, acc);
        d3 = x2q + x2j[r0+3] - 2.f*acc;
      }
      float m4 = fminf(fminf(d0,d1), fminf(d2,d3));
      if (__any(m4 < g9)){
        const int jj = j0 + r0;
        kpush(b0,b1,b2,b3,cnt, bk, g9, d0, jj);
        kpush(b0,b1,b2,b3,cnt, bk, g9, d1, jj+1);
        kpush(b0,b1,b2,b3,cnt, bk, g9, d2, jj+2);
        kpush(b0,b1,b2,b3,cnt, bk, g9, d3, jj+3);
      }
    }
  }

  if (__any(cnt > 0)) kins_raw(bk, b0);
  if (__any(cnt > 1)) kins_raw(bk, b1);
  if (__any(cnt > 2)) kins_raw(bk, b2);
  if (__any(cnt > 3)) kins_raw(bk, b3);

  __syncthreads();
  #pragma unroll
  for (int u=0;u<10;++u) lst[(size_t)(w*16 + lm)*40 + kg*10 + u] = bk[u];
  __syncthreads();
  if (tid < 64) {
    const double* row = &lst[(size_t)tid*40];
    int i0=0, i1=0, i2=0, i3=0;
    size_t base = ((size_t)jh*(4*NPTS) + bbase + q0 + tid)*10;
    #pragma unroll
    for (int u=0;u<10;++u){
      double ka = row[i0], kb2 = row[10+i1], kc2 = row[20+i2], kd2 = row[30+i3];
      bool tab = ka  < kb2; double mab = tab ? ka  : kb2;
      bool tcd = kc2 < kd2; double mcd = tcd ? kc2 : kd2;
      bool tt  = mab < mcd; double m   = tt  ? mab : mcd;
      pk[base+u] = m;
      i0 += (tt && tab)  ? 1 : 0;
      i1 += (tt && !tab) ? 1 : 0;
      i2 += (!tt && tcd) ? 1 : 0;
      i3 += (!tt && !tcd)? 1 : 0;
    }
  }
}

// ---------- merge the 2 j-half partial f64-key lists -> final idx ----------
__global__ __launch_bounds__(256) void knnmerge_kernel(const double* __restrict__ pk,
                                                       int* __restrict__ idxout){
  int p = blockIdx.x*256 + threadIdx.x;   // 0..32767
  const double* A = pk + (size_t)p*10;
  const double* B = pk + (size_t)(4*NPTS)*10 + (size_t)p*10;
  int ia=0, ib=0;
  int* op = idxout + (size_t)p*10;
  #pragma unroll
  for (int u=0;u<10;++u){
    double ka = A[ia], kb = B[ib];
    bool t = ka < kb;
    op[u] = (int)(__double_as_longlong(t ? ka : kb) & 8191LL);
    ia += t ? 1 : 0; ib += t ? 0 : 1;
  }
}

// ---------- prep U/D for 64-ch edge conv (wave-per-point, lane-per-output) ----------
__global__ __launch_bounds__(256) void prepUD64_kernel(const float* __restrict__ XC, int cin,
                                                       const float* __restrict__ W,
                                                       float* __restrict__ U,
                                                       float* __restrict__ D){
  const int tid = threadIdx.x;
  const int w = tid >> 6, o = tid & 63;
  const int p = blockIdx.x*4 + w;
  const float* xr = XC + (size_t)p*192 + cin;   // wave-uniform base
  float zu = 0.f, zd = 0.f;
  #pragma unroll
  for (int c=0;c<64;++c){
    float xc = xr[c];                  // uniform across the wave
    float wt = W[c*64 + o];
    float wb = W[(64+c)*64 + o];
    zu = fmaf(xc, wt, zu);
    zd = fmaf(xc, wb - wt, zd);
  }
  U[(size_t)p*64 + o] = zu;
  D[(size_t)p*64 + o] = zd;
}

// ---------- prep U/D for conv1 ----------
__global__ __launch_bounds__(256) void prepUD12_kernel(const float* __restrict__ T,
                                                       const float* __restrict__ W1,
                                                       float* __restrict__ U,
                                                       float* __restrict__ D){
  int p = blockIdx.x*256 + threadIdx.x;
  float t[3] = {T[p*3+0], T[p*3+1], T[p*3+2]};
  const float4* W = (const float4*)W1;
  float4 u[16], q[16];
  #pragma unroll
  for (int o=0;o<16;++o){ u[o]=make_float4(0,0,0,0); q[o]=make_float4(0,0,0,0); }
  #pragma unroll
  for (int c=0;c<3;++c){
    const float tc = t[c];
    #pragma unroll
    for (int o=0;o<16;++o){
      float4 ws  = W[c*16+o],     ws2 = W[(c+3)*16+o];
      float4 wq  = W[(c+6)*16+o], wq2 = W[(c+9)*16+o];
      u[o] = f4fma(tc, make_float4(ws.x+ws2.x, ws.y+ws2.y, ws.z+ws2.z, ws.w+ws2.w), u[o]);
      q[o] = f4fma(tc, make_float4(wq.x+wq2.x, wq.y+wq2.y, wq.z+wq2.z, wq.w+wq2.w), q[o]);
    }
  }
  float4* up = (float4*)(U + (size_t)p*64);
  float4* dp = (float4*)(D + (size_t)p*64);
  #pragma unroll
  for (int o=0;o<16;++o){
    up[o] = u[o];
    dp[o] = make_float4(q[o].x-u[o].x, q[o].y-u[o].y, q[o].z-u[o].z, q[o].w-u[o].w);
  }
}

// ---------- two-layer edge conv + fused sqnorm + fused bf16 hi/lo split ----------
__global__ __launch_bounds__(256) void edge2w_kernel(const float* __restrict__ U,
                                                     const float* __restrict__ Dp,
                                                     const int* __restrict__ idx,
                                                     const float* __restrict__ Wb,
                                                     const float* __restrict__ PA, int paa, int pab,
                                                     float* __restrict__ out, int coff,
                                                     float* __restrict__ sqnout,
                                                     unsigned short* __restrict__ Xh,
                                                     unsigned short* __restrict__ Xl){
  __shared__ __align__(16) float sh[4][10][68];
  const int tid = threadIdx.x;
  const int w = tid >> 6, o = tid & 63;
  const int p = blockIdx.x*4 + w, b = p >> 13;
  const float aa = PA[paa], ab = PA[pab];

  float wreg[64];
  #pragma unroll
  for (int c=0;c<64;++c) wreg[c] = Wb[c*64 + o];

  const float dc = Dp[(size_t)p*64 + o];

  #pragma unroll
  for (int k=0;k<10;++k){
    int nb = idx[p*10 + k];
    float u = U[((size_t)(b<<13)+nb)*64 + o];
    sh[w][k][o] = preluf(u + dc, aa);
  }
  __syncthreads();

  float mx = -INFINITY;
  #pragma unroll 2
  for (int k=0;k<10;++k){
    float a0=0.f,a1=0.f,a2=0.f,a3=0.f;
    #pragma unroll
    for (int c4=0;c4<16;++c4){
      float4 hv = *(const float4*)&sh[w][k][c4*4];
      a0 = fmaf(hv.x, wreg[c4*4+0], a0);
      a1 = fmaf(hv.y, wreg[c4*4+1], a1);
      a2 = fmaf(hv.z, wreg[c4*4+2], a2);
      a3 = fmaf(hv.w, wreg[c4*4+3], a3);
    }
    float z = (a0+a1)+(a2+a3);
    mx = fmaxf(mx, preluf(z, ab));
  }
  out[(size_t)p*192 + coff + o] = mx;
  // fused bf16 hi/lo split of the output (feeds next conv's KNN GEMM)
  {
    unsigned um = __float_as_uint(mx);
    unsigned h  = (um + 0x7FFFu + ((um>>16)&1u)) & 0xFFFF0000u;
    float rr = mx - __uint_as_float(h);
    unsigned ur = __float_as_uint(rr);
    unsigned l  = (ur + 0x7FFFu + ((ur>>16)&1u)) >> 16;
    Xh[(size_t)p*64 + o] = (unsigned short)(h >> 16);
    Xl[(size_t)p*64 + o] = (unsigned short)l;
  }
  // fused sqnorm of this 64-col output row
  float sq = mx*mx;
  #pragma unroll
  for (int off=1; off<64; off<<=1) sq += __shfl_xor(sq, off);
  if (o == 0) sqnout[p] = sq;
}

// ---------- single-layer edge conv (conv3), wave-per-point ----------
__global__ __launch_bounds__(256) void edge1w_kernel(const float* __restrict__ U,
                                                     const float* __restrict__ Dp,
                                                     const int* __restrict__ idx,
                                                     const float* __restrict__ PA, int paa,
                                                     float* __restrict__ out, int coff){
  const int tid = threadIdx.x;
  const int w = tid >> 6, o = tid & 63;
  const int p = blockIdx.x*4 + w, b = p >> 13;
  const float aa = PA[paa];
  const float dc = Dp[(size_t)p*64 + o];
  float mx = -INFINITY;
  #pragma unroll
  for (int k=0;k<10;++k){
    int nb = idx[p*10 + k];
    float u = U[((size_t)(b<<13)+nb)*64 + o];
    mx = fmaxf(mx, preluf(u + dc, aa));
  }
  out[(size_t)p*192 + coff + o] = mx;
}

// ---------- fused weight prep: all four head weights -> hi/lo transposed ----------
__global__ __launch_bounds__(256) void prepWall_kernel(const float* __restrict__ W6,
                                                       const float* __restrict__ W7,
                                                       const float* __restrict__ W8,
                                                       const float* __restrict__ W9,
                                                       unsigned short* __restrict__ Wh6, unsigned short* __restrict__ Wl6,
                                                       unsigned short* __restrict__ Wh7, unsigned short* __restrict__ Wl7,
                                                       unsigned short* __restrict__ Wh8, unsigned short* __restrict__ Wl8,
                                                       unsigned short* __restrict__ Wh9, unsigned short* __restrict__ Wl9){
  int bb = blockIdx.x;
  const float* W; unsigned short *Wh, *Wl; int K, N, k;
  if (bb < 192)      { W=W6; Wh=Wh6; Wl=Wl6; K=192; N=1024; k=bb; }
  else if (bb < 384) { W=W7; Wh=Wh7; Wl=Wl7; K=192; N=256;  k=bb-192; }
  else if (bb < 640) { W=W8; Wh=Wh8; Wl=Wl8; K=256; N=256;  k=bb-384; }
  else               { W=W9; Wh=Wh9; Wl=Wl9; K=256; N=128;  k=bb-640; }
  for (int n = threadIdx.x; n < N; n += 256){
    float v = W[(size_t)k*N + n];
    unsigned ua = __float_as_uint(v);
    unsigned h = (ua + 0x7FFFu + ((ua>>16)&1u)) & 0xFFFF0000u;
    float r = v - __uint_as_float(h);
    unsigned ub = __float_as_uint(r);
    unsigned l = (ub + 0x7FFFu + ((ub>>16)&1u)) >> 16;
    Wh[(size_t)n*K + k] = (unsigned short)(h >> 16);
    Wl[(size_t)n*K + k] = (unsigned short)l;
  }
}

// ---------- MFMA bf16 hi/lo GEMM: C = prelu(A@W [+bias]); EPI2: colmax partials ----------
template<int EPI>
__global__ __launch_bounds__(256, 2) void mgemm_kernel(const float* __restrict__ A, int lda,
                                                       const unsigned short* __restrict__ WhT,
                                                       const unsigned short* __restrict__ WlT,
                                                       int K,
                                                       float* __restrict__ C, int ldc,
                                                       const float* __restrict__ bias,
                                                       const float* __restrict__ PA, int pidx,
                                                       int Ntot){
  __shared__ __align__(16) unsigned char smem[73728];
  unsigned short* sa = (unsigned short*)smem;
  unsigned short* sb = (unsigned short*)(smem + 36864);
  float* cst = (float*)smem;

  const int tid = threadIdx.x;
  const int m0 = blockIdx.x*128, n0 = blockIdx.y*128;
  const int L = tid & 63, w = tid >> 6;
  const int lm = L & 15, kg = L >> 4;

  f32x4 acc[2][8];
  #pragma unroll
  for (int mt=0;mt<2;++mt)
    #pragma unroll
    for (int nt=0;nt<8;++nt) acc[mt][nt] = (f32x4){0.f,0.f,0.f,0.f};

  for (int c0 = 0; c0 < K; c0 += 64) {
    __syncthreads();
    #pragma unroll
    for (int s=0;s<8;++s){
      int e = tid + s*256;
      int r = e >> 4, kq = (e & 15) << 2;
      float4 v = *(const float4*)(A + (size_t)(m0+r)*lda + c0 + kq);
      unsigned lo01, lo23;
      unsigned hi01 = bfsplit2(v.x, v.y, lo01);
      unsigned hi23 = bfsplit2(v.z, v.w, lo23);
      uint2 hp; hp.x = hi01; hp.y = hi23;
      uint2 lp; lp.x = lo01; lp.y = lo23;
      *(uint2*)&sa[r*72 + kq]        = hp;
      *(uint2*)&sa[9216 + r*72 + kq] = lp;
    }
    #pragma unroll
    for (int s=0;s<4;++s){
      int e = tid + s*256;
      int col = e >> 3, ko = (e & 7) << 3;
      *(uint4*)&sb[col*72 + ko]        = *(const uint4*)&WhT[(size_t)(n0+col)*K + c0 + ko];
      *(uint4*)&sb[9216 + col*72 + ko] = *(const uint4*)&WlT[(size_t)(n0+col)*K + c0 + ko];
    }
    __syncthreads();

    #pragma unroll
    for (int kc=0;kc<2;++kc){
      const int ko = kc*32 + kg*8;
      bf16x8s ah[2], al[2];
      #pragma unroll
      for (int mt=0;mt<2;++mt){
        int q = w*32 + mt*16 + lm;
        ah[mt] = *(const bf16x8s*)&sa[q*72 + ko];
        al[mt] = *(const bf16x8s*)&sa[9216 + q*72 + ko];
      }
      #pragma unroll
      for (int nt=0;nt<8;++nt){
        int n = nt*16 + lm;
        bf16x8s bh = *(const bf16x8s*)&sb[n*72 + ko];
        bf16x8s bl = *(const bf16x8s*)&sb[9216 + n*72 + ko];
        #pragma unroll
        for (int mt=0;mt<2;++mt){
          acc[mt][nt] = __builtin_amdgcn_mfma_f32_16x16x32_bf16(ah[mt], bh, acc[mt][nt], 0,0,0);
          acc[mt][nt] = __builtin_amdgcn_mfma_f32_16x16x32_bf16(ah[mt], bl, acc[mt][nt], 0,0,0);
          acc[mt][nt] = __builtin_amdgcn_mfma_f32_16x16x32_bf16(al[mt], bh, acc[mt][nt], 0,0,0);
        }
      }
    }
  }
  __syncthreads();

  const float a = PA[pidx];
  if (EPI == 2) {
    #pragma unroll
    for (int nt=0;nt<8;++nt){
      f32x4 c0v = acc[0][nt], c1v = acc[1][nt];
      float m = -INFINITY;
      #pragma unroll
      for (int r=0;r<4;++r){ m = fmaxf(m, preluf(c0v[r], a)); m = fmaxf(m, preluf(c1v[r], a)); }
      m = fmaxf(m, __shfl_xor(m, 16));
      m = fmaxf(m, __shfl_xor(m, 32));
      if (kg == 0) cst[w*128 + nt*16 + lm] = m;
    }
    __syncthreads();
    if (tid < 128){
      float m = fmaxf(fmaxf(cst[tid], cst[128+tid]), fmaxf(cst[256+tid], cst[384+tid]));
      C[(size_t)blockIdx.x*Ntot + n0 + tid] = m;
    }
  } else {
    float bc[8];
    if (EPI == 1){
      int bb = m0 >> 13;
      #pragma unroll
      for (int nt=0;nt<8;++nt) bc[nt] = bias[bb*256 + n0 + nt*16 + lm];
    }
    #pragma unroll
    for (int mt=0;mt<2;++mt){
      #pragma unroll
      for (int nt=0;nt<8;++nt){
        f32x4 c = acc[mt][nt];
        int col = nt*16 + lm;
        #pragma unroll
        for (int r=0;r<4;++r){
          int row = w*32 + mt*16 + kg*4 + r;
          float v = c[r] + (EPI==1 ? bc[nt] : 0.f);
          cst[row*132 + col] = preluf(v, a);
        }
      }
    }
    __syncthreads();
    const int tm = tid & 15, tn = tid >> 4;
    #pragma unroll
    for (int i=0;i<8;++i){
      int row = tm*8 + i;
      float4 v0 = *(const float4*)&cst[row*132 + tn*8];
      float4 v1 = *(const float4*)&cst[row*132 + tn*8 + 4];
      float* cp = C + (size_t)(m0 + row)*ldc + n0 + tn*8;
      *(float4*)cp     = v0;
      *(float4*)(cp+4) = v1;
    }
  }
}

__global__ __launch_bounds__(256) void reduce_pmax(const float* __restrict__ pmax,
                                                   float* __restrict__ x5m){
  int t = blockIdx.x*256 + threadIdx.x;
  if (t < 4096) {
    int b = t >> 10, o = t & 1023;
    float m = -INFINITY;
    for (int mt=0; mt<64; ++mt) m = fmaxf(m, pmax[((size_t)(b*64+mt))*1024 + o]);
    x5m[t] = m;
  }
}

__global__ __launch_bounds__(256) void bias7_kernel(const float* __restrict__ x5m,
                                                    const float* __restrict__ W7,
                                                    float* __restrict__ b7){
  int b = blockIdx.x; int o = threadIdx.x;
  float s = 0.f;
  for (int j=0;j<1024;++j) s = fmaf(x5m[b*1024+j], W7[(size_t)(192+j)*256 + o], s);
  b7[b*256+o] = s;
}

__global__ __launch_bounds__(256) void final10_kernel(const float* __restrict__ y3,
                                                      const float* __restrict__ W10,
                                                      const float* __restrict__ PA,
                                                      float* __restrict__ out){
  int p = blockIdx.x*256 + threadIdx.x;
  const float4* r = (const float4*)(y3 + (size_t)p*128);
  float s0=0.f, s1=0.f;
  #pragma unroll
  for (int c4=0;c4<32;++c4){
    float4 v = r[c4];
    s0 = fmaf(v.x, W10[(c4*4+0)*2+0], s0); s1 = fmaf(v.x, W10[(c4*4+0)*2+1], s1);
    s0 = fmaf(v.y, W10[(c4*4+1)*2+0], s0); s1 = fmaf(v.y, W10[(c4*4+1)*2+1], s1);
    s0 = fmaf(v.z, W10[(c4*4+2)*2+0], s0); s1 = fmaf(v.z, W10[(c4*4+2)*2+1], s1);
    s0 = fmaf(v.w, W10[(c4*4+3)*2+0], s0); s1 = fmaf(v.w, W10[(c4*4+3)*2+1], s1);
  }
  float a = PA[9];
  out[p*2+0] = s0>=0.f? s0 : a*s0;
  out[p*2+1] = s1>=0.f? s1 : a*s1;
}

extern "C" void kernel_launch(void* const* d_in, const int* in_sizes, int n_in,
                              void* d_out, int out_size, void* d_ws, size_t ws_size,
                              hipStream_t stream) {
  const float* T   = (const float*)d_in[0];
  const float* W1  = (const float*)d_in[1];
  const float* W2  = (const float*)d_in[2];
  const float* W3  = (const float*)d_in[3];
  const float* W4  = (const float*)d_in[4];
  const float* W5  = (const float*)d_in[5];
  const float* W6  = (const float*)d_in[6];
  const float* W7  = (const float*)d_in[7];
  const float* W8  = (const float*)d_in[8];
  const float* W9  = (const float*)d_in[9];
  const float* W10 = (const float*)d_in[10];
  const float* PA  = (const float*)d_in[11];

  float* ws   = (float*)d_ws;
  float* x0   = ws + 0;                // 131072
  float* sqn0 = ws + 131072;           // 32768
  float* sqn1 = ws + 163840;           // 32768
  float* sqn2 = ws + 196608;           // 32768
  int*   idx0 = (int*)(ws + 229376);   // 327680
  int*   idx1 = (int*)(ws + 557056);   // 327680
  int*   idx2 = (int*)(ws + 884736);   // 327680
  float* xcat = ws + 1212416;          // 6291456  [B,N,192]
  float* pmax = ws + 7503872;          // 262144
  float* x5m  = ws + 7766016;          // 4096
  float* b7   = ws + 7770112;          // 1024
  float* y1   = ws + 7771136;          // 8388608 floats (aliased: U / pk / Xh / Xl)
  float* y2   = ws + 16159744;         // 8388608  (aliased: D)
  float* y3   = xcat;
  float* U    = y1;                            // [32768][64] f32 = 2M floats
  float* D    = y2;
  double* pk  = (double*)y1;                   // [2][32768][10] f64 = 1.31M floats
  unsigned short* Xh = (unsigned short*)(y1 + 3145728);  // 4 MB, floats [3.0M,4.0M)
  unsigned short* Xl = (unsigned short*)(y1 + 4194304);  // 4 MB, floats [4.0M,5.0M)

  // split/transposed weights: reuse idx region (dead after edge1w)
  unsigned short* wsc = (unsigned short*)(ws + 229376);
  unsigned short* Wh6 = wsc;
  unsigned short* Wl6 = wsc + 196608;
  unsigned short* Wh7 = wsc + 393216;
  unsigned short* Wl7 = wsc + 442368;
  unsigned short* Wh8 = wsc + 491520;
  unsigned short* Wl8 = wsc + 557056;
  unsigned short* Wh9 = wsc + 622592;
  unsigned short* Wl9 = wsc + 655360;

  // conv1
  prep0_kernel<<<128, 256, 0, stream>>>(T, x0, sqn0);
  knn4_kernel<<<dim3(128,4,2), 256, 0, stream>>>(x0, sqn0, pk);
  knnmerge_kernel<<<128, 256, 0, stream>>>(pk, idx0);
  prepUD12_kernel<<<128, 256, 0, stream>>>(T, W1, U, D);
  edge2w_kernel<<<8192, 256, 0, stream>>>(U, D, idx0, W2, PA, 0, 1, xcat, 0, sqn1, Xh, Xl);

  // conv2
  knn64_kernel<<<dim3(128,4,2), 256, 0, stream>>>(Xh, Xl, sqn1, pk);
  knnmerge_kernel<<<128, 256, 0, stream>>>(pk, idx1);
  prepUD64_kernel<<<8192, 256, 0, stream>>>(xcat, 0, W3, U, D);
  edge2w_kernel<<<8192, 256, 0, stream>>>(U, D, idx1, W4, PA, 2, 3, xcat, 64, sqn2, Xh, Xl);

  // conv3
  knn64_kernel<<<dim3(128,4,2), 256, 0, stream>>>(Xh, Xl, sqn2, pk);
  knnmerge_kernel<<<128, 256, 0, stream>>>(pk, idx2);
  prepUD64_kernel<<<8192, 256, 0, stream>>>(xcat, 64, W5, U, D);
  edge1w_kernel<<<8192, 256, 0, stream>>>(U, D, idx2, PA, 4, xcat, 128);

  // head weights -> bf16 hi/lo transposed (one fused launch)
  prepWall_kernel<<<896, 256, 0, stream>>>(W6, W7, W8, W9,
                                           Wh6, Wl6, Wh7, Wl7, Wh8, Wl8, Wh9, Wl9);

  // head
  mgemm_kernel<2><<<dim3(256,8), 256, 0, stream>>>(xcat, 192, Wh6, Wl6, 192, pmax, 0, nullptr, PA, 5, 1024);
  reduce_pmax<<<16, 256, 0, stream>>>(pmax, x5m);
  bias7_kernel<<<4, 256, 0, stream>>>(x5m, W7, b7);
  mgemm_kernel<1><<<dim3(256,2), 256, 0, stream>>>(xcat, 192, Wh7, Wl7, 192, y1, 256, b7, PA, 6, 0);
  mgemm_kernel<0><<<dim3(256,2), 256, 0, stream>>>(y1, 256, Wh8, Wl8, 256, y2, 256, nullptr, PA, 7, 0);
  mgemm_kernel<0><<<dim3(256,1), 256, 0, stream>>>(y2, 256, Wh9, Wl9, 256, y3, 128, nullptr, PA, 8, 0);
  final10_kernel<<<128, 256, 0, stream>>>(y3, W10, PA, (float*)d_out);
}